// Round 2
// baseline (876.552 us; speedup 1.0000x reference)
//
#include <hip/hip_runtime.h>
#include <hip/hip_bf16.h>
#include <stdint.h>

#define NH 16
#define NKV 8
#define HD 128
#define BB 4
#define SS 1024
#define CTXL 2048
#define LT 3072
#define HID 2048
#define QKVN 4096
#define MROWS 4096

typedef __hip_bfloat16 bf16;
using f32x4 = __attribute__((ext_vector_type(4))) float;
using s16x8 = __attribute__((ext_vector_type(8))) short;

#define MFMA(a, b, c) __builtin_amdgcn_mfma_f32_16x16x32_bf16((a), (b), (c), 0, 0, 0)

__device__ __forceinline__ void gload_lds16(const void* g, void* l) {
  __builtin_amdgcn_global_load_lds((const __attribute__((address_space(1))) void*)g,
                                   (__attribute__((address_space(3))) void*)l, 16, 0, 0);
}

__device__ __forceinline__ void store_bf8(bf16* dst, const float* f) {
  bf16 tmp[8];
#pragma unroll
  for (int j = 0; j < 8; ++j) tmp[j] = __float2bfloat16(f[j]);
  __builtin_memcpy((void*)dst, (const void*)tmp, 16);
}

// ---------------- prep kernels ----------------

__global__ void cvt_bf16(const float* __restrict__ in, bf16* __restrict__ out) {
  size_t tid = (size_t)blockIdx.x * 256 + threadIdx.x;  // one thread per 8 elems
  const float4* p = (const float4*)(in + tid * 8);
  float4 a = p[0], b = p[1];
  float f[8] = {a.x, a.y, a.z, a.w, b.x, b.y, b.z, b.w};
  store_bf8(out + tid * 8, f);
}

// out[c][r] = (bf16) in[r][c]
__global__ void transpose_cvt(const float* __restrict__ in, bf16* __restrict__ out,
                              int R, int C) {
  __shared__ float tile[32][33];
  int c0 = blockIdx.x * 32, r0 = blockIdx.y * 32;
  int tx = threadIdx.x & 31, ty = threadIdx.x >> 5;
#pragma unroll
  for (int i = 0; i < 32; i += 8)
    tile[ty + i][tx] = in[(size_t)(r0 + ty + i) * C + c0 + tx];
  __syncthreads();
#pragma unroll
  for (int i = 0; i < 32; i += 8)
    out[(size_t)(c0 + ty + i) * R + r0 + tx] = __float2bfloat16(tile[tx][ty + i]);
}

// ctx_k [b][l][h][d] f32 -> K_full [b][h][l][d] bf16 (l < CTXL)
__global__ void ctxk_copy(const float* __restrict__ ck, bf16* __restrict__ Kf) {
  int tid = blockIdx.x * 256 + threadIdx.x;
  int d8 = tid & 15, l = (tid >> 4) & 2047, h = (tid >> 15) & 7, b = tid >> 18;
  const float* s = ck + (((size_t)b * CTXL + l) * NKV + h) * HD + d8 * 8;
  const float4* p = (const float4*)s;
  float4 a = p[0], bb = p[1];
  float f[8] = {a.x, a.y, a.z, a.w, bb.x, bb.y, bb.z, bb.w};
  store_bf8(Kf + (((size_t)(b * NKV + h)) * LT + l) * HD + d8 * 8, f);
}

// ctx_v [b][l][h][d] f32 -> V_T [b][h][d][l] bf16 (l < CTXL)
__global__ void ctxv_transpose(const float* __restrict__ cv, bf16* __restrict__ Vt) {
  __shared__ float tile[32][33];
  int l0 = blockIdx.x * 32, d0 = blockIdx.y * 32;
  int b = blockIdx.z >> 3, h = blockIdx.z & 7;
  int tx = threadIdx.x & 31, ty = threadIdx.x >> 5;
#pragma unroll
  for (int i = 0; i < 32; i += 8)
    tile[ty + i][tx] = cv[(((size_t)b * CTXL + l0 + ty + i) * NKV + h) * HD + d0 + tx];
  __syncthreads();
#pragma unroll
  for (int i = 0; i < 32; i += 8)
    Vt[(((size_t)(b * NKV + h)) * HD + d0 + ty + i) * LT + l0 + tx] =
        __float2bfloat16(tile[tx][ty + i]);
}

// qkv v-slice -> V_T tail (l = CTXL + s)
__global__ void vt_from_qkv(const bf16* __restrict__ qkv, bf16* __restrict__ Vt) {
  __shared__ float tile[32][33];
  int s0 = blockIdx.x * 32, d0 = blockIdx.y * 32;
  int b = blockIdx.z >> 3, h = blockIdx.z & 7;
  int tx = threadIdx.x & 31, ty = threadIdx.x >> 5;
#pragma unroll
  for (int i = 0; i < 32; i += 8)
    tile[ty + i][tx] = __bfloat162float(
        qkv[((size_t)b * SS + s0 + ty + i) * QKVN + 3072 + h * HD + d0 + tx]);
  __syncthreads();
#pragma unroll
  for (int i = 0; i < 32; i += 8)
    Vt[(((size_t)(b * NKV + h)) * HD + d0 + ty + i) * LT + CTXL + s0 + tx] =
        __float2bfloat16(tile[tx][ty + i]);
}

__global__ void rope_table(const int* __restrict__ pid, float* __restrict__ cosT,
                           float* __restrict__ sinT) {
  int tid = blockIdx.x * 256 + threadIdx.x;  // S*64
  int j = tid & 63, s = tid >> 6;
  int sec = (j < 8) ? 0 : (j < 16) ? 1 : (j < 40) ? 2 : 3;
  float pos = (float)pid[sec * SS + s];
  float inv = __expf(-(float)j * 0.14391156831212787f);  // ln(10000)/64
  float a = pos * inv;
  cosT[tid] = cosf(a);
  sinT[tid] = sinf(a);
}

__global__ void rope_q(const bf16* __restrict__ qkv, const float* __restrict__ cosT,
                       const float* __restrict__ sinT, bf16* __restrict__ Q) {
  int tid = blockIdx.x * 256 + threadIdx.x;
  int j = tid & 63, h = (tid >> 6) & 15, s = (tid >> 10) & 1023, b = tid >> 20;
  const bf16* src = qkv + ((size_t)b * SS + s) * QKVN + h * HD;
  float x1 = __bfloat162float(src[j]), x2 = __bfloat162float(src[j + 64]);
  float c = cosT[s * 64 + j], sn = sinT[s * 64 + j];
  bf16* dst = Q + (((size_t)(b * NH + h)) * SS + s) * HD;
  dst[j] = __float2bfloat16(x1 * c - x2 * sn);
  dst[j + 64] = __float2bfloat16(x2 * c + x1 * sn);
}

__global__ void rope_k(const bf16* __restrict__ qkv, const float* __restrict__ cosT,
                       const float* __restrict__ sinT, bf16* __restrict__ Kf) {
  int tid = blockIdx.x * 256 + threadIdx.x;
  int j = tid & 63, h = (tid >> 6) & 7, s = (tid >> 9) & 1023, b = tid >> 19;
  const bf16* src = qkv + ((size_t)b * SS + s) * QKVN + 2048 + h * HD;
  float x1 = __bfloat162float(src[j]), x2 = __bfloat162float(src[j + 64]);
  float c = cosT[s * 64 + j], sn = sinT[s * 64 + j];
  bf16* dst = Kf + (((size_t)(b * NKV + h)) * LT + CTXL + s) * HD;
  dst[j] = __float2bfloat16(x1 * c - x2 * sn);
  dst[j + 64] = __float2bfloat16(x2 * c + x1 * sn);
}

// ---------------- GEMM: C[M][N] = A[M][K] * BT[N][K]^T ----------------

template <typename OT>
__global__ void gemm_bt(const bf16* __restrict__ A, const bf16* __restrict__ BT,
                        OT* __restrict__ C, int M, int N, int K) {
  __shared__ __attribute__((aligned(16))) short lA[128 * 64];
  __shared__ __attribute__((aligned(16))) short lB[128 * 64];
  const int t = threadIdx.x;
  const int lane = t & 63, w = t >> 6;
  const int wm = w >> 1, wn = w & 1;
  const int lrow = lane & 15, kgrp = lane >> 4;
  const int m0 = blockIdx.y * 128, n0 = blockIdx.x * 128;
  const int rowA = w * 32 + (lane >> 3);  // +c*8 per staging call
  const int kch = (lane & 7) * 8;
  const f32x4 fz = {0.f, 0.f, 0.f, 0.f};
  f32x4 acc[4][4];
#pragma unroll
  for (int i = 0; i < 4; ++i)
#pragma unroll
    for (int j = 0; j < 4; ++j) acc[i][j] = fz;

  for (int k0 = 0; k0 < K; k0 += 64) {
    const bf16* Ag = A + (size_t)(m0 + rowA) * K + k0 + kch;
    const bf16* Bg = BT + (size_t)(n0 + rowA) * K + k0 + kch;
#pragma unroll
    for (int c = 0; c < 4; ++c) {
      gload_lds16(Ag + (size_t)(c * 8) * K, &lA[(w * 32 + c * 8) * 64]);
      gload_lds16(Bg + (size_t)(c * 8) * K, &lB[(w * 32 + c * 8) * 64]);
    }
    __syncthreads();
#pragma unroll
    for (int kk = 0; kk < 64; kk += 32) {
      s16x8 af[4], bfr[4];
#pragma unroll
      for (int i = 0; i < 4; ++i)
        af[i] = *(const s16x8*)&lA[(wm * 64 + i * 16 + lrow) * 64 + kk + kgrp * 8];
#pragma unroll
      for (int j = 0; j < 4; ++j)
        bfr[j] = *(const s16x8*)&lB[(wn * 64 + j * 16 + lrow) * 64 + kk + kgrp * 8];
#pragma unroll
      for (int i = 0; i < 4; ++i)
#pragma unroll
        for (int j = 0; j < 4; ++j) acc[i][j] = MFMA(af[i], bfr[j], acc[i][j]);
    }
    __syncthreads();
  }
#pragma unroll
  for (int i = 0; i < 4; ++i)
#pragma unroll
    for (int j = 0; j < 4; ++j)
#pragma unroll
      for (int r = 0; r < 4; ++r) {
        int row = m0 + wm * 64 + i * 16 + kgrp * 4 + r;
        int col = n0 + wn * 64 + j * 16 + lrow;
        float v = acc[i][j][r];
        if constexpr (sizeof(OT) == 2)
          C[(size_t)row * N + col] = __float2bfloat16(v);
        else
          C[(size_t)row * N + col] = v;
      }
}

// ---------------- flash attention ----------------
// 64 q-rows per block, 4 waves x 16 rows, KVBLK=64, NO barriers (P tile is
// strictly per-wave; in-wave LDS write->read ordering is lgkmcnt-enforced).

#define PSTR 72  // P row stride in elements: 144B = 16B-aligned, conflict-lite

__global__ void flash_attn(const bf16* __restrict__ Q, const bf16* __restrict__ Kf,
                           const bf16* __restrict__ Vt, bf16* __restrict__ O) {
  __shared__ __attribute__((aligned(16))) bf16 P_lds[4][16][PSTR];
  const int t = threadIdx.x, lane = t & 63, w = t >> 6;
  const int qb = blockIdx.x & 15, h = (blockIdx.x >> 4) & 15, b = blockIdx.x >> 8;
  const int hk = h >> 1;
  const int lrow = lane & 15, kgrp = lane >> 4;
  const bf16* Qp = Q + (((size_t)(b * NH + h)) * SS + qb * 64 + w * 16) * HD;
  s16x8 qf[4];
#pragma unroll
  for (int kd = 0; kd < 4; ++kd)
    qf[kd] = *(const s16x8*)&Qp[lrow * HD + kd * 32 + kgrp * 8];
  const f32x4 fz = {0.f, 0.f, 0.f, 0.f};
  f32x4 acc[8];
#pragma unroll
  for (int i = 0; i < 8; ++i) acc[i] = fz;
  float m_[4], l_[4];
#pragma unroll
  for (int r = 0; r < 4; ++r) { m_[r] = -1e30f; l_[r] = 0.f; }
  const bf16* Kp = Kf + (size_t)(b * NKV + hk) * LT * HD;
  const bf16* Vp = Vt + (size_t)(b * NKV + hk) * HD * LT;

  for (int l0 = 0; l0 < LT; l0 += 64) {
    f32x4 sc[4];
#pragma unroll
    for (int cf = 0; cf < 4; ++cf) sc[cf] = fz;
#pragma unroll
    for (int cf = 0; cf < 4; ++cf)
#pragma unroll
      for (int kd = 0; kd < 4; ++kd) {
        s16x8 kb = *(const s16x8*)&Kp[(size_t)(l0 + cf * 16 + lrow) * HD + kd * 32 + kgrp * 8];
        sc[cf] = MFMA(qf[kd], kb, sc[cf]);
      }
    const float scale = 0.08838834764831845f;
    float p[4][4], so[4];
#pragma unroll
    for (int r = 0; r < 4; ++r) {
      float s0 = sc[0][r] * scale, s1 = sc[1][r] * scale;
      float s2 = sc[2][r] * scale, s3 = sc[3][r] * scale;
      float mx = fmaxf(fmaxf(s0, s1), fmaxf(s2, s3));
#pragma unroll
      for (int off = 1; off < 16; off <<= 1) mx = fmaxf(mx, __shfl_xor(mx, off, 16));
      float mn = fmaxf(m_[r], mx);
      so[r] = __expf(m_[r] - mn);
      p[0][r] = __expf(s0 - mn);
      p[1][r] = __expf(s1 - mn);
      p[2][r] = __expf(s2 - mn);
      p[3][r] = __expf(s3 - mn);
      float rs = p[0][r] + p[1][r] + p[2][r] + p[3][r];
#pragma unroll
      for (int off = 1; off < 16; off <<= 1) rs += __shfl_xor(rs, off, 16);
      l_[r] = l_[r] * so[r] + rs;
      m_[r] = mn;
    }
#pragma unroll
    for (int i = 0; i < 8; ++i)
#pragma unroll
      for (int r = 0; r < 4; ++r) acc[i][r] *= so[r];
#pragma unroll
    for (int r = 0; r < 4; ++r)
#pragma unroll
      for (int cf = 0; cf < 4; ++cf)
        P_lds[w][kgrp * 4 + r][cf * 16 + lrow] = __float2bfloat16(p[cf][r]);
    // per-wave LDS: no barrier needed; lgkmcnt orders write->read in-wave
    s16x8 pa[2];
#pragma unroll
    for (int kc = 0; kc < 2; ++kc)
      pa[kc] = *(const s16x8*)&P_lds[w][lrow][kc * 32 + kgrp * 8];
#pragma unroll
    for (int nd = 0; nd < 8; ++nd)
#pragma unroll
      for (int kc = 0; kc < 2; ++kc) {
        s16x8 vb = *(const s16x8*)&Vp[(size_t)(nd * 16 + lrow) * LT + l0 + kc * 32 + kgrp * 8];
        acc[nd] = MFMA(pa[kc], vb, acc[nd]);
      }
  }
#pragma unroll
  for (int nd = 0; nd < 8; ++nd)
#pragma unroll
    for (int r = 0; r < 4; ++r) {
      int row = qb * 64 + w * 16 + kgrp * 4 + r;
      O[((size_t)b * SS + row) * 2048 + h * HD + nd * 16 + lrow] =
          __float2bfloat16(acc[nd][r] / l_[r]);
    }
}

// ---------------- launch ----------------

extern "C" void kernel_launch(void* const* d_in, const int* in_sizes, int n_in,
                              void* d_out, int out_size, void* d_ws, size_t ws_size,
                              hipStream_t stream) {
  const float* hs = (const float*)d_in[0];
  const float* Wqkv = (const float*)d_in[1];
  const float* Wo = (const float*)d_in[2];
  const float* ctx_k = (const float*)d_in[3];
  const float* ctx_v = (const float*)d_in[4];
  const int* pid = (const int*)d_in[5];
  float* out = (float*)d_out;
  char* ws = (char*)d_ws;

  bf16* Hb = (bf16*)(ws);                      // 16.78 MB (reused as attn_out)
  bf16* WqT = (bf16*)(ws + 16777216);          // 16.78 MB
  bf16* WoT = (bf16*)(ws + 33554432);          // 8.39 MB
  bf16* qkv = (bf16*)(ws + 41943040);          // 33.55 MB
  bf16* Qb = (bf16*)(ws + 75497472);           // 16.78 MB
  bf16* Kfull = (bf16*)(ws + 92274688);        // 25.17 MB
  bf16* Vt = (bf16*)(ws + 117440512);          // 25.17 MB
  float* cosT = (float*)(ws + 142606336);      // 256 KB
  float* sinT = (float*)(ws + 142606336 + 262144);
  bf16* attn = Hb;  // alias: Hb dead after QKV GEMM

  rope_table<<<256, 256, 0, stream>>>(pid, cosT, sinT);
  cvt_bf16<<<4096, 256, 0, stream>>>(hs, Hb);
  transpose_cvt<<<dim3(128, 64), 256, 0, stream>>>(Wqkv, WqT, HID, QKVN);
  transpose_cvt<<<dim3(64, 64), 256, 0, stream>>>(Wo, WoT, 2048, 2048);
  ctxk_copy<<<4096, 256, 0, stream>>>(ctx_k, Kfull);
  ctxv_transpose<<<dim3(64, 4, 32), 256, 0, stream>>>(ctx_v, Vt);
  gemm_bt<bf16><<<dim3(QKVN / 128, MROWS / 128), 256, 0, stream>>>(
      Hb, WqT, qkv, MROWS, QKVN, HID);
  rope_q<<<16384, 256, 0, stream>>>(qkv, cosT, sinT, Qb);
  rope_k<<<8192, 256, 0, stream>>>(qkv, cosT, sinT, Kfull);
  vt_from_qkv<<<dim3(32, 4, 32), 256, 0, stream>>>(qkv, Vt);
  flash_attn<<<1024, 256, 0, stream>>>(Qb, Kfull, Vt, attn);
  gemm_bt<float><<<dim3(2048 / 128, MROWS / 128), 256, 0, stream>>>(
      attn, WoT, out, MROWS, 2048, HID);
}

// Round 3
// 479.237 us; speedup vs baseline: 1.8291x; 1.8291x over previous
//
#include <hip/hip_runtime.h>
#include <hip/hip_bf16.h>
#include <stdint.h>

#define NH 16
#define NKV 8
#define HD 128
#define BB 4
#define SS 1024
#define CTXL 2048
#define LT 3072
#define HID 2048
#define QKVN 4096
#define MROWS 4096

typedef __hip_bfloat16 bf16;
using f32x4 = __attribute__((ext_vector_type(4))) float;
using s16x8 = __attribute__((ext_vector_type(8))) short;

#define MFMA(a, b, c) __builtin_amdgcn_mfma_f32_16x16x32_bf16((a), (b), (c), 0, 0, 0)

__device__ __forceinline__ void gload_lds16(const void* g, void* l) {
  __builtin_amdgcn_global_load_lds((const __attribute__((address_space(1))) void*)g,
                                   (__attribute__((address_space(3))) void*)l, 16, 0, 0);
}

__device__ __forceinline__ void store_bf8(bf16* dst, const float* f) {
  bf16 tmp[8];
#pragma unroll
  for (int j = 0; j < 8; ++j) tmp[j] = __float2bfloat16(f[j]);
  __builtin_memcpy((void*)dst, (const void*)tmp, 16);
}

// ---------------- prep kernels ----------------

__global__ void cvt_bf16(const float* __restrict__ in, bf16* __restrict__ out) {
  size_t tid = (size_t)blockIdx.x * 256 + threadIdx.x;  // one thread per 8 elems
  const float4* p = (const float4*)(in + tid * 8);
  float4 a = p[0], b = p[1];
  float f[8] = {a.x, a.y, a.z, a.w, b.x, b.y, b.z, b.w};
  store_bf8(out + tid * 8, f);
}

// out[c][r] = (bf16) in[r][c]
__global__ void transpose_cvt(const float* __restrict__ in, bf16* __restrict__ out,
                              int R, int C) {
  __shared__ float tile[32][33];
  int c0 = blockIdx.x * 32, r0 = blockIdx.y * 32;
  int tx = threadIdx.x & 31, ty = threadIdx.x >> 5;
#pragma unroll
  for (int i = 0; i < 32; i += 8)
    tile[ty + i][tx] = in[(size_t)(r0 + ty + i) * C + c0 + tx];
  __syncthreads();
#pragma unroll
  for (int i = 0; i < 32; i += 8)
    out[(size_t)(c0 + ty + i) * R + r0 + tx] = __float2bfloat16(tile[tx][ty + i]);
}

// ctx_k [b][l][h][d] f32 -> K_full [b][h][l][d] bf16 (l < CTXL)
__global__ void ctxk_copy(const float* __restrict__ ck, bf16* __restrict__ Kf) {
  int tid = blockIdx.x * 256 + threadIdx.x;
  int d8 = tid & 15, l = (tid >> 4) & 2047, h = (tid >> 15) & 7, b = tid >> 18;
  const float* s = ck + (((size_t)b * CTXL + l) * NKV + h) * HD + d8 * 8;
  const float4* p = (const float4*)s;
  float4 a = p[0], bb = p[1];
  float f[8] = {a.x, a.y, a.z, a.w, bb.x, bb.y, bb.z, bb.w};
  store_bf8(Kf + (((size_t)(b * NKV + h)) * LT + l) * HD + d8 * 8, f);
}

// ctx_v [b][l][h][d] f32 -> V_T [b][h][d][l] bf16 (l < CTXL)
__global__ void ctxv_transpose(const float* __restrict__ cv, bf16* __restrict__ Vt) {
  __shared__ float tile[32][33];
  int l0 = blockIdx.x * 32, d0 = blockIdx.y * 32;
  int b = blockIdx.z >> 3, h = blockIdx.z & 7;
  int tx = threadIdx.x & 31, ty = threadIdx.x >> 5;
#pragma unroll
  for (int i = 0; i < 32; i += 8)
    tile[ty + i][tx] = cv[(((size_t)b * CTXL + l0 + ty + i) * NKV + h) * HD + d0 + tx];
  __syncthreads();
#pragma unroll
  for (int i = 0; i < 32; i += 8)
    Vt[(((size_t)(b * NKV + h)) * HD + d0 + ty + i) * LT + l0 + tx] =
        __float2bfloat16(tile[tx][ty + i]);
}

// qkv v-slice -> V_T tail (l = CTXL + s)
__global__ void vt_from_qkv(const bf16* __restrict__ qkv, bf16* __restrict__ Vt) {
  __shared__ float tile[32][33];
  int s0 = blockIdx.x * 32, d0 = blockIdx.y * 32;
  int b = blockIdx.z >> 3, h = blockIdx.z & 7;
  int tx = threadIdx.x & 31, ty = threadIdx.x >> 5;
#pragma unroll
  for (int i = 0; i < 32; i += 8)
    tile[ty + i][tx] = __bfloat162float(
        qkv[((size_t)b * SS + s0 + ty + i) * QKVN + 3072 + h * HD + d0 + tx]);
  __syncthreads();
#pragma unroll
  for (int i = 0; i < 32; i += 8)
    Vt[(((size_t)(b * NKV + h)) * HD + d0 + ty + i) * LT + CTXL + s0 + tx] =
        __float2bfloat16(tile[tx][ty + i]);
}

__global__ void rope_table(const int* __restrict__ pid, float* __restrict__ cosT,
                           float* __restrict__ sinT) {
  int tid = blockIdx.x * 256 + threadIdx.x;  // S*64
  int j = tid & 63, s = tid >> 6;
  int sec = (j < 8) ? 0 : (j < 16) ? 1 : (j < 40) ? 2 : 3;
  float pos = (float)pid[sec * SS + s];
  float inv = __expf(-(float)j * 0.14391156831212787f);  // ln(10000)/64
  float a = pos * inv;
  cosT[tid] = cosf(a);
  sinT[tid] = sinf(a);
}

__global__ void rope_q(const bf16* __restrict__ qkv, const float* __restrict__ cosT,
                       const float* __restrict__ sinT, bf16* __restrict__ Q) {
  int tid = blockIdx.x * 256 + threadIdx.x;
  int j = tid & 63, h = (tid >> 6) & 15, s = (tid >> 10) & 1023, b = tid >> 20;
  const bf16* src = qkv + ((size_t)b * SS + s) * QKVN + h * HD;
  float x1 = __bfloat162float(src[j]), x2 = __bfloat162float(src[j + 64]);
  float c = cosT[s * 64 + j], sn = sinT[s * 64 + j];
  bf16* dst = Q + (((size_t)(b * NH + h)) * SS + s) * HD;
  dst[j] = __float2bfloat16(x1 * c - x2 * sn);
  dst[j + 64] = __float2bfloat16(x2 * c + x1 * sn);
}

__global__ void rope_k(const bf16* __restrict__ qkv, const float* __restrict__ cosT,
                       const float* __restrict__ sinT, bf16* __restrict__ Kf) {
  int tid = blockIdx.x * 256 + threadIdx.x;
  int j = tid & 63, h = (tid >> 6) & 7, s = (tid >> 9) & 1023, b = tid >> 19;
  const bf16* src = qkv + ((size_t)b * SS + s) * QKVN + 2048 + h * HD;
  float x1 = __bfloat162float(src[j]), x2 = __bfloat162float(src[j + 64]);
  float c = cosT[s * 64 + j], sn = sinT[s * 64 + j];
  bf16* dst = Kf + (((size_t)(b * NKV + h)) * LT + CTXL + s) * HD;
  dst[j] = __float2bfloat16(x1 * c - x2 * sn);
  dst[j + 64] = __float2bfloat16(x2 * c + x1 * sn);
}

// ---------------- GEMM: C[M][N] = A[M][K] * BT[N][K]^T ----------------

template <typename OT>
__global__ void gemm_bt(const bf16* __restrict__ A, const bf16* __restrict__ BT,
                        OT* __restrict__ C, int M, int N, int K) {
  __shared__ __attribute__((aligned(16))) short lA[128 * 64];
  __shared__ __attribute__((aligned(16))) short lB[128 * 64];
  const int t = threadIdx.x;
  const int lane = t & 63, w = t >> 6;
  const int wm = w >> 1, wn = w & 1;
  const int lrow = lane & 15, kgrp = lane >> 4;
  const int m0 = blockIdx.y * 128, n0 = blockIdx.x * 128;
  const int rowA = w * 32 + (lane >> 3);  // +c*8 per staging call
  const int kch = (lane & 7) * 8;
  const f32x4 fz = {0.f, 0.f, 0.f, 0.f};
  f32x4 acc[4][4];
#pragma unroll
  for (int i = 0; i < 4; ++i)
#pragma unroll
    for (int j = 0; j < 4; ++j) acc[i][j] = fz;

  for (int k0 = 0; k0 < K; k0 += 64) {
    const bf16* Ag = A + (size_t)(m0 + rowA) * K + k0 + kch;
    const bf16* Bg = BT + (size_t)(n0 + rowA) * K + k0 + kch;
#pragma unroll
    for (int c = 0; c < 4; ++c) {
      gload_lds16(Ag + (size_t)(c * 8) * K, &lA[(w * 32 + c * 8) * 64]);
      gload_lds16(Bg + (size_t)(c * 8) * K, &lB[(w * 32 + c * 8) * 64]);
    }
    __syncthreads();
#pragma unroll
    for (int kk = 0; kk < 64; kk += 32) {
      s16x8 af[4], bfr[4];
#pragma unroll
      for (int i = 0; i < 4; ++i)
        af[i] = *(const s16x8*)&lA[(wm * 64 + i * 16 + lrow) * 64 + kk + kgrp * 8];
#pragma unroll
      for (int j = 0; j < 4; ++j)
        bfr[j] = *(const s16x8*)&lB[(wn * 64 + j * 16 + lrow) * 64 + kk + kgrp * 8];
#pragma unroll
      for (int i = 0; i < 4; ++i)
#pragma unroll
        for (int j = 0; j < 4; ++j) acc[i][j] = MFMA(af[i], bfr[j], acc[i][j]);
    }
    __syncthreads();
  }
#pragma unroll
  for (int i = 0; i < 4; ++i)
#pragma unroll
    for (int j = 0; j < 4; ++j)
#pragma unroll
      for (int r = 0; r < 4; ++r) {
        int row = m0 + wm * 64 + i * 16 + kgrp * 4 + r;
        int col = n0 + wn * 64 + j * 16 + lrow;
        float v = acc[i][j][r];
        if constexpr (sizeof(OT) == 2)
          C[(size_t)row * N + col] = __float2bfloat16(v);
        else
          C[(size_t)row * N + col] = v;
      }
}

// ---------------- flash attention ----------------
// 64 q-rows/block, 4 waves x 16 rows, KVBLK=64. K and V tiles double-buffered
// in LDS via async global_load_lds (stage t+1 during compute of t; one
// vmcnt(0)+barrier per tile). XOR chunk swizzle (16B chunks) applied at BOTH
// the pre-swizzled global source and the ds_read (rule 21): K chunk^(row&15),
// V chunk^(row&7) -> conflict-free ds_read_b128.

#define PSTR 72  // P row stride in elements: 144B = 16B-aligned
#define NT 48    // LT / 64

__global__ void flash_attn(const bf16* __restrict__ Q, const bf16* __restrict__ Kf,
                           const bf16* __restrict__ Vt, bf16* __restrict__ O) {
  __shared__ __attribute__((aligned(16))) bf16 Kl[2][64][128];   // 32 KB
  __shared__ __attribute__((aligned(16))) bf16 Vl[2][128][64];   // 32 KB
  __shared__ __attribute__((aligned(16))) bf16 P_lds[4][16][PSTR];
  const int t = threadIdx.x, lane = t & 63, w = t >> 6;
  const int qb = blockIdx.x & 15, h = (blockIdx.x >> 4) & 15, b = blockIdx.x >> 8;
  const int hk = h >> 1;
  const int lrow = lane & 15, kgrp = lane >> 4;
  const bf16* Kp = Kf + (size_t)(b * NKV + hk) * LT * HD;
  const bf16* Vp = Vt + (size_t)(b * NKV + hk) * HD * LT;

  // staging lane geometry
  const int krow_off = lane >> 4;                    // 0..3 rows within group
  const int kchunk = lane & 15;                      // 16B chunk within K row
  const int vrow_off = lane >> 3;                    // 0..7 rows within group
  const int vchunk = (lane & 7) ^ (vrow_off & 7);    // pre-swizzled V source

  const bf16* Qp = Q + (((size_t)(b * NH + h)) * SS + qb * 64 + w * 16) * HD;
  s16x8 qf[4];
#pragma unroll
  for (int kd = 0; kd < 4; ++kd)
    qf[kd] = *(const s16x8*)&Qp[lrow * HD + kd * 32 + kgrp * 8];

  const f32x4 fz = {0.f, 0.f, 0.f, 0.f};
  f32x4 acc[8];
#pragma unroll
  for (int i = 0; i < 8; ++i) acc[i] = fz;
  float m_[4], l_[4];
#pragma unroll
  for (int r = 0; r < 4; ++r) { m_[r] = -1e30f; l_[r] = 0.f; }

#define STAGE(buf, l0)                                                         \
  do {                                                                         \
    _Pragma("unroll") for (int c = 0; c < 4; ++c) {                            \
      int row = w * 16 + c * 4 + krow_off;                                     \
      gload_lds16(Kp + (size_t)((l0) + row) * HD + (kchunk ^ (row & 15)) * 8,  \
                  &Kl[buf][w * 16 + c * 4][0]);                                \
    }                                                                          \
    _Pragma("unroll") for (int c = 0; c < 4; ++c) {                            \
      int d = w * 32 + c * 8 + vrow_off;                                       \
      gload_lds16(Vp + (size_t)d * LT + (l0) + vchunk * 8,                     \
                  &Vl[buf][w * 32 + c * 8][0]);                                \
    }                                                                          \
  } while (0)

  STAGE(0, 0);
  __syncthreads();  // drains vmcnt before barrier

  for (int tt = 0; tt < NT; ++tt) {
    const int cur = tt & 1;
    const int l0n = (tt + 1) * 64;
    if (tt + 1 < NT) STAGE(cur ^ 1, l0n);

    f32x4 sc[4];
#pragma unroll
    for (int cf = 0; cf < 4; ++cf) sc[cf] = fz;
#pragma unroll
    for (int cf = 0; cf < 4; ++cf)
#pragma unroll
      for (int kd = 0; kd < 4; ++kd) {
        s16x8 kb =
            *(const s16x8*)&Kl[cur][cf * 16 + lrow][((kd * 4 + kgrp) ^ lrow) * 8];
        sc[cf] = MFMA(qf[kd], kb, sc[cf]);
      }
    const float scale = 0.08838834764831845f;
    float p[4][4], so[4];
#pragma unroll
    for (int r = 0; r < 4; ++r) {
      float s0 = sc[0][r] * scale, s1 = sc[1][r] * scale;
      float s2 = sc[2][r] * scale, s3 = sc[3][r] * scale;
      float mx = fmaxf(fmaxf(s0, s1), fmaxf(s2, s3));
#pragma unroll
      for (int off = 1; off < 16; off <<= 1) mx = fmaxf(mx, __shfl_xor(mx, off, 16));
      float mn = fmaxf(m_[r], mx);
      so[r] = __expf(m_[r] - mn);
      p[0][r] = __expf(s0 - mn);
      p[1][r] = __expf(s1 - mn);
      p[2][r] = __expf(s2 - mn);
      p[3][r] = __expf(s3 - mn);
      float rs = p[0][r] + p[1][r] + p[2][r] + p[3][r];
#pragma unroll
      for (int off = 1; off < 16; off <<= 1) rs += __shfl_xor(rs, off, 16);
      l_[r] = l_[r] * so[r] + rs;
      m_[r] = mn;
    }
#pragma unroll
    for (int i = 0; i < 8; ++i)
#pragma unroll
      for (int r = 0; r < 4; ++r) acc[i][r] *= so[r];
#pragma unroll
    for (int r = 0; r < 4; ++r)
#pragma unroll
      for (int cf = 0; cf < 4; ++cf)
        P_lds[w][kgrp * 4 + r][cf * 16 + lrow] = __float2bfloat16(p[cf][r]);
    // per-wave LDS: in-wave write->read ordering via lgkmcnt, no barrier
    s16x8 pa[2];
#pragma unroll
    for (int kc = 0; kc < 2; ++kc)
      pa[kc] = *(const s16x8*)&P_lds[w][lrow][kc * 32 + kgrp * 8];
#pragma unroll
    for (int nd = 0; nd < 8; ++nd)
#pragma unroll
      for (int kc = 0; kc < 2; ++kc) {
        s16x8 vb = *(const s16x8*)&Vl[cur][nd * 16 + lrow]
                                     [((kc * 4 + kgrp) ^ (lrow & 7)) * 8];
        acc[nd] = MFMA(pa[kc], vb, acc[nd]);
      }
    __syncthreads();  // vmcnt(0)+lgkmcnt(0) drain: staged tile tt+1 ready
  }
#undef STAGE

#pragma unroll
  for (int nd = 0; nd < 8; ++nd)
#pragma unroll
    for (int r = 0; r < 4; ++r) {
      int row = qb * 64 + w * 16 + kgrp * 4 + r;
      O[((size_t)b * SS + row) * 2048 + h * HD + nd * 16 + lrow] =
          __float2bfloat16(acc[nd][r] / l_[r]);
    }
}

// ---------------- launch ----------------

extern "C" void kernel_launch(void* const* d_in, const int* in_sizes, int n_in,
                              void* d_out, int out_size, void* d_ws, size_t ws_size,
                              hipStream_t stream) {
  const float* hs = (const float*)d_in[0];
  const float* Wqkv = (const float*)d_in[1];
  const float* Wo = (const float*)d_in[2];
  const float* ctx_k = (const float*)d_in[3];
  const float* ctx_v = (const float*)d_in[4];
  const int* pid = (const int*)d_in[5];
  float* out = (float*)d_out;
  char* ws = (char*)d_ws;

  bf16* Hb = (bf16*)(ws);                      // 16.78 MB (reused as attn_out)
  bf16* WqT = (bf16*)(ws + 16777216);          // 16.78 MB
  bf16* WoT = (bf16*)(ws + 33554432);          // 8.39 MB
  bf16* qkv = (bf16*)(ws + 41943040);          // 33.55 MB
  bf16* Qb = (bf16*)(ws + 75497472);           // 16.78 MB
  bf16* Kfull = (bf16*)(ws + 92274688);        // 25.17 MB
  bf16* Vt = (bf16*)(ws + 117440512);          // 25.17 MB
  float* cosT = (float*)(ws + 142606336);      // 256 KB
  float* sinT = (float*)(ws + 142606336 + 262144);
  bf16* attn = Hb;  // alias: Hb dead after QKV GEMM

  rope_table<<<256, 256, 0, stream>>>(pid, cosT, sinT);
  cvt_bf16<<<4096, 256, 0, stream>>>(hs, Hb);
  transpose_cvt<<<dim3(128, 64), 256, 0, stream>>>(Wqkv, WqT, HID, QKVN);
  transpose_cvt<<<dim3(64, 64), 256, 0, stream>>>(Wo, WoT, 2048, 2048);
  ctxk_copy<<<4096, 256, 0, stream>>>(ctx_k, Kfull);
  ctxv_transpose<<<dim3(64, 4, 32), 256, 0, stream>>>(ctx_v, Vt);
  gemm_bt<bf16><<<dim3(QKVN / 128, MROWS / 128), 256, 0, stream>>>(
      Hb, WqT, qkv, MROWS, QKVN, HID);
  rope_q<<<16384, 256, 0, stream>>>(qkv, cosT, sinT, Qb);
  rope_k<<<8192, 256, 0, stream>>>(qkv, cosT, sinT, Kfull);
  vt_from_qkv<<<dim3(32, 4, 32), 256, 0, stream>>>(qkv, Vt);
  flash_attn<<<1024, 256, 0, stream>>>(Qb, Kfull, Vt, attn);
  gemm_bt<float><<<dim3(2048 / 128, MROWS / 128), 256, 0, stream>>>(
      attn, WoT, out, MROWS, 2048, HID);
}

// Round 4
// 413.911 us; speedup vs baseline: 2.1177x; 1.1578x over previous
//
#include <hip/hip_runtime.h>
#include <hip/hip_bf16.h>
#include <stdint.h>

#define NH 16
#define NKV 8
#define HD 128
#define BB 4
#define SS 1024
#define CTXL 2048
#define LT 3072
#define HID 2048
#define QKVN 4096
#define MROWS 4096

typedef __hip_bfloat16 bf16;
using f32x4 = __attribute__((ext_vector_type(4))) float;
using s16x8 = __attribute__((ext_vector_type(8))) short;

#define MFMA(a, b, c) __builtin_amdgcn_mfma_f32_16x16x32_bf16((a), (b), (c), 0, 0, 0)

__device__ __forceinline__ void gload_lds16(const void* g, void* l) {
  __builtin_amdgcn_global_load_lds((const __attribute__((address_space(1))) void*)g,
                                   (__attribute__((address_space(3))) void*)l, 16, 0, 0);
}

__device__ __forceinline__ void store_bf8(bf16* dst, const float* f) {
  bf16 tmp[8];
#pragma unroll
  for (int j = 0; j < 8; ++j) tmp[j] = __float2bfloat16(f[j]);
  __builtin_memcpy((void*)dst, (const void*)tmp, 16);
}

// ---------------- prep kernels ----------------

__global__ void cvt_bf16(const float* __restrict__ in, bf16* __restrict__ out) {
  size_t tid = (size_t)blockIdx.x * 256 + threadIdx.x;  // one thread per 8 elems
  const float4* p = (const float4*)(in + tid * 8);
  float4 a = p[0], b = p[1];
  float f[8] = {a.x, a.y, a.z, a.w, b.x, b.y, b.z, b.w};
  store_bf8(out + tid * 8, f);
}

// out[c][r] = (bf16) in[r][c]
__global__ void transpose_cvt(const float* __restrict__ in, bf16* __restrict__ out,
                              int R, int C) {
  __shared__ float tile[32][33];
  int c0 = blockIdx.x * 32, r0 = blockIdx.y * 32;
  int tx = threadIdx.x & 31, ty = threadIdx.x >> 5;
#pragma unroll
  for (int i = 0; i < 32; i += 8)
    tile[ty + i][tx] = in[(size_t)(r0 + ty + i) * C + c0 + tx];
  __syncthreads();
#pragma unroll
  for (int i = 0; i < 32; i += 8)
    out[(size_t)(c0 + ty + i) * R + r0 + tx] = __float2bfloat16(tile[tx][ty + i]);
}

// ctx_k [b][l][h][d] f32 -> K_full [b][h][l][d] bf16 (l < CTXL)
__global__ void ctxk_copy(const float* __restrict__ ck, bf16* __restrict__ Kf) {
  int tid = blockIdx.x * 256 + threadIdx.x;
  int d8 = tid & 15, l = (tid >> 4) & 2047, h = (tid >> 15) & 7, b = tid >> 18;
  const float* s = ck + (((size_t)b * CTXL + l) * NKV + h) * HD + d8 * 8;
  const float4* p = (const float4*)s;
  float4 a = p[0], bb = p[1];
  float f[8] = {a.x, a.y, a.z, a.w, bb.x, bb.y, bb.z, bb.w};
  store_bf8(Kf + (((size_t)(b * NKV + h)) * LT + l) * HD + d8 * 8, f);
}

// ctx_v [b][l][h][d] f32 -> V_T [b][h][d][l] bf16 (l < CTXL)
__global__ void ctxv_transpose(const float* __restrict__ cv, bf16* __restrict__ Vt) {
  __shared__ float tile[32][33];
  int l0 = blockIdx.x * 32, d0 = blockIdx.y * 32;
  int b = blockIdx.z >> 3, h = blockIdx.z & 7;
  int tx = threadIdx.x & 31, ty = threadIdx.x >> 5;
#pragma unroll
  for (int i = 0; i < 32; i += 8)
    tile[ty + i][tx] = cv[(((size_t)b * CTXL + l0 + ty + i) * NKV + h) * HD + d0 + tx];
  __syncthreads();
#pragma unroll
  for (int i = 0; i < 32; i += 8)
    Vt[(((size_t)(b * NKV + h)) * HD + d0 + ty + i) * LT + l0 + tx] =
        __float2bfloat16(tile[tx][ty + i]);
}

// qkv v-slice -> V_T tail (l = CTXL + s)
__global__ void vt_from_qkv(const bf16* __restrict__ qkv, bf16* __restrict__ Vt) {
  __shared__ float tile[32][33];
  int s0 = blockIdx.x * 32, d0 = blockIdx.y * 32;
  int b = blockIdx.z >> 3, h = blockIdx.z & 7;
  int tx = threadIdx.x & 31, ty = threadIdx.x >> 5;
#pragma unroll
  for (int i = 0; i < 32; i += 8)
    tile[ty + i][tx] = __bfloat162float(
        qkv[((size_t)b * SS + s0 + ty + i) * QKVN + 3072 + h * HD + d0 + tx]);
  __syncthreads();
#pragma unroll
  for (int i = 0; i < 32; i += 8)
    Vt[(((size_t)(b * NKV + h)) * HD + d0 + ty + i) * LT + CTXL + s0 + tx] =
        __float2bfloat16(tile[tx][ty + i]);
}

__global__ void rope_table(const int* __restrict__ pid, float* __restrict__ cosT,
                           float* __restrict__ sinT) {
  int tid = blockIdx.x * 256 + threadIdx.x;  // S*64
  int j = tid & 63, s = tid >> 6;
  int sec = (j < 8) ? 0 : (j < 16) ? 1 : (j < 40) ? 2 : 3;
  float pos = (float)pid[sec * SS + s];
  float inv = __expf(-(float)j * 0.14391156831212787f);  // ln(10000)/64
  float a = pos * inv;
  cosT[tid] = cosf(a);
  sinT[tid] = sinf(a);
}

__global__ void rope_q(const bf16* __restrict__ qkv, const float* __restrict__ cosT,
                       const float* __restrict__ sinT, bf16* __restrict__ Q) {
  int tid = blockIdx.x * 256 + threadIdx.x;
  int j = tid & 63, h = (tid >> 6) & 15, s = (tid >> 10) & 1023, b = tid >> 20;
  const bf16* src = qkv + ((size_t)b * SS + s) * QKVN + h * HD;
  float x1 = __bfloat162float(src[j]), x2 = __bfloat162float(src[j + 64]);
  float c = cosT[s * 64 + j], sn = sinT[s * 64 + j];
  bf16* dst = Q + (((size_t)(b * NH + h)) * SS + s) * HD;
  dst[j] = __float2bfloat16(x1 * c - x2 * sn);
  dst[j + 64] = __float2bfloat16(x2 * c + x1 * sn);
}

__global__ void rope_k(const bf16* __restrict__ qkv, const float* __restrict__ cosT,
                       const float* __restrict__ sinT, bf16* __restrict__ Kf) {
  int tid = blockIdx.x * 256 + threadIdx.x;
  int j = tid & 63, h = (tid >> 6) & 7, s = (tid >> 9) & 1023, b = tid >> 19;
  const bf16* src = qkv + ((size_t)b * SS + s) * QKVN + 2048 + h * HD;
  float x1 = __bfloat162float(src[j]), x2 = __bfloat162float(src[j + 64]);
  float c = cosT[s * 64 + j], sn = sinT[s * 64 + j];
  bf16* dst = Kf + (((size_t)(b * NKV + h)) * LT + CTXL + s) * HD;
  dst[j] = __float2bfloat16(x1 * c - x2 * sn);
  dst[j + 64] = __float2bfloat16(x2 * c + x1 * sn);
}

// ---------------- GEMM: C[M][N] = A[M][K] * BT[N][K]^T ----------------

template <typename OT>
__global__ void gemm_bt(const bf16* __restrict__ A, const bf16* __restrict__ BT,
                        OT* __restrict__ C, int M, int N, int K) {
  __shared__ __attribute__((aligned(16))) short lA[128 * 64];
  __shared__ __attribute__((aligned(16))) short lB[128 * 64];
  const int t = threadIdx.x;
  const int lane = t & 63, w = t >> 6;
  const int wm = w >> 1, wn = w & 1;
  const int lrow = lane & 15, kgrp = lane >> 4;
  const int m0 = blockIdx.y * 128, n0 = blockIdx.x * 128;
  const int rowA = w * 32 + (lane >> 3);  // +c*8 per staging call
  const int kch = (lane & 7) * 8;
  const f32x4 fz = {0.f, 0.f, 0.f, 0.f};
  f32x4 acc[4][4];
#pragma unroll
  for (int i = 0; i < 4; ++i)
#pragma unroll
    for (int j = 0; j < 4; ++j) acc[i][j] = fz;

  for (int k0 = 0; k0 < K; k0 += 64) {
    const bf16* Ag = A + (size_t)(m0 + rowA) * K + k0 + kch;
    const bf16* Bg = BT + (size_t)(n0 + rowA) * K + k0 + kch;
#pragma unroll
    for (int c = 0; c < 4; ++c) {
      gload_lds16(Ag + (size_t)(c * 8) * K, &lA[(w * 32 + c * 8) * 64]);
      gload_lds16(Bg + (size_t)(c * 8) * K, &lB[(w * 32 + c * 8) * 64]);
    }
    __syncthreads();
#pragma unroll
    for (int kk = 0; kk < 64; kk += 32) {
      s16x8 af[4], bfr[4];
#pragma unroll
      for (int i = 0; i < 4; ++i)
        af[i] = *(const s16x8*)&lA[(wm * 64 + i * 16 + lrow) * 64 + kk + kgrp * 8];
#pragma unroll
      for (int j = 0; j < 4; ++j)
        bfr[j] = *(const s16x8*)&lB[(wn * 64 + j * 16 + lrow) * 64 + kk + kgrp * 8];
#pragma unroll
      for (int i = 0; i < 4; ++i)
#pragma unroll
        for (int j = 0; j < 4; ++j) acc[i][j] = MFMA(af[i], bfr[j], acc[i][j]);
    }
    __syncthreads();
  }
#pragma unroll
  for (int i = 0; i < 4; ++i)
#pragma unroll
    for (int j = 0; j < 4; ++j)
#pragma unroll
      for (int r = 0; r < 4; ++r) {
        int row = m0 + wm * 64 + i * 16 + kgrp * 4 + r;
        int col = n0 + wn * 64 + j * 16 + lrow;
        float v = acc[i][j][r];
        if constexpr (sizeof(OT) == 2)
          C[(size_t)row * N + col] = __float2bfloat16(v);
        else
          C[(size_t)row * N + col] = v;
      }
}

// ---------------- flash attention ----------------
// 128 q-rows/block, 8 waves x 16 rows, KVBLK=64. K double-buffered, V
// single-buffered (V(t) staged during QK/softmax of t, read after barrier1).
// LDS 66 KB -> 2 blocks/CU = 16 waves/CU. XOR chunk swizzle on both sides
// (rule 21): K chunk^(row&15), V chunk^(row&7).

#define PSTR 72  // P row stride in elements: 144B = 16B-aligned
#define NT 48    // LT / 64

__global__ void flash_attn(const bf16* __restrict__ Q, const bf16* __restrict__ Kf,
                           const bf16* __restrict__ Vt, bf16* __restrict__ O) {
  __shared__ __attribute__((aligned(16))) bf16 Kl[2][64][128];  // 32 KB
  __shared__ __attribute__((aligned(16))) bf16 Vl[128][64];     // 16 KB
  __shared__ __attribute__((aligned(16))) bf16 P_lds[8][16][PSTR];  // 18 KB
  const int t = threadIdx.x, lane = t & 63, w = t >> 6;
  const int qb = blockIdx.x & 7, h = (blockIdx.x >> 3) & 15, b = blockIdx.x >> 7;
  const int hk = h >> 1;
  const int lrow = lane & 15, kgrp = lane >> 4;
  const bf16* Kp = Kf + (size_t)(b * NKV + hk) * LT * HD;
  const bf16* Vp = Vt + (size_t)(b * NKV + hk) * HD * LT;

  const bf16* Qp = Q + (((size_t)(b * NH + h)) * SS + qb * 128 + w * 16) * HD;
  s16x8 qf[4];
#pragma unroll
  for (int kd = 0; kd < 4; ++kd)
    qf[kd] = *(const s16x8*)&Qp[lrow * HD + kd * 32 + kgrp * 8];

  const f32x4 fz = {0.f, 0.f, 0.f, 0.f};
  f32x4 acc[8];
#pragma unroll
  for (int i = 0; i < 8; ++i) acc[i] = fz;
  float m_[4], l_[4];
#pragma unroll
  for (int r = 0; r < 4; ++r) { m_[r] = -1e30f; l_[r] = 0.f; }

  // staging geometry (8 waves, 512 threads)
  // K: 64 rows x 16 chunks; per wave rows w*8 + c*4 + (lane>>4), c=0..1
  // V: 128 rows x 8 chunks; per wave rows w*16 + c*8 + (lane>>3), c=0..1
#define STAGE_K(buf, l0)                                                        \
  do {                                                                          \
    _Pragma("unroll") for (int c = 0; c < 2; ++c) {                             \
      int row = w * 8 + c * 4 + (lane >> 4);                                    \
      gload_lds16(Kp + (size_t)((l0) + row) * HD + ((lane & 15) ^ (row & 15)) * 8, \
                  &Kl[buf][w * 8 + c * 4][0]);                                  \
    }                                                                           \
  } while (0)
#define STAGE_V(l0)                                                             \
  do {                                                                          \
    _Pragma("unroll") for (int c = 0; c < 2; ++c) {                             \
      int d = w * 16 + c * 8 + (lane >> 3);                                     \
      gload_lds16(Vp + (size_t)d * LT + (l0) + ((lane & 7) ^ (d & 7)) * 8,      \
                  &Vl[w * 16 + c * 8][0]);                                      \
    }                                                                           \
  } while (0)

  STAGE_K(0, 0);
  __syncthreads();

  for (int tt = 0; tt < NT; ++tt) {
    const int cur = tt & 1;
    STAGE_V(tt * 64);
    if (tt + 1 < NT) STAGE_K(cur ^ 1, (tt + 1) * 64);

    f32x4 sc[4];
#pragma unroll
    for (int cf = 0; cf < 4; ++cf) sc[cf] = fz;
#pragma unroll
    for (int cf = 0; cf < 4; ++cf)
#pragma unroll
      for (int kd = 0; kd < 4; ++kd) {
        s16x8 kb =
            *(const s16x8*)&Kl[cur][cf * 16 + lrow][((kd * 4 + kgrp) ^ lrow) * 8];
        sc[cf] = MFMA(qf[kd], kb, sc[cf]);
      }
    const float scale = 0.08838834764831845f;
    float p[4][4], so[4];
#pragma unroll
    for (int r = 0; r < 4; ++r) {
      float s0 = sc[0][r] * scale, s1 = sc[1][r] * scale;
      float s2 = sc[2][r] * scale, s3 = sc[3][r] * scale;
      float mx = fmaxf(fmaxf(s0, s1), fmaxf(s2, s3));
#pragma unroll
      for (int off = 1; off < 16; off <<= 1) mx = fmaxf(mx, __shfl_xor(mx, off, 16));
      float mn = fmaxf(m_[r], mx);
      so[r] = __expf(m_[r] - mn);
      p[0][r] = __expf(s0 - mn);
      p[1][r] = __expf(s1 - mn);
      p[2][r] = __expf(s2 - mn);
      p[3][r] = __expf(s3 - mn);
      float rs = p[0][r] + p[1][r] + p[2][r] + p[3][r];
#pragma unroll
      for (int off = 1; off < 16; off <<= 1) rs += __shfl_xor(rs, off, 16);
      l_[r] = l_[r] * so[r] + rs;
      m_[r] = mn;
    }
#pragma unroll
    for (int i = 0; i < 8; ++i)
#pragma unroll
      for (int r = 0; r < 4; ++r) acc[i][r] *= so[r];
#pragma unroll
    for (int r = 0; r < 4; ++r)
#pragma unroll
      for (int cf = 0; cf < 4; ++cf)
        P_lds[w][kgrp * 4 + r][cf * 16 + lrow] = __float2bfloat16(p[cf][r]);
    // per-wave LDS: in-wave write->read ordering via lgkmcnt, no barrier
    s16x8 pa[2];
#pragma unroll
    for (int kc = 0; kc < 2; ++kc)
      pa[kc] = *(const s16x8*)&P_lds[w][lrow][kc * 32 + kgrp * 8];

    __syncthreads();  // drains V(tt) + K(tt+1) DMA (vmcnt 0) before PV

#pragma unroll
    for (int nd = 0; nd < 8; ++nd)
#pragma unroll
      for (int kc = 0; kc < 2; ++kc) {
        s16x8 vb =
            *(const s16x8*)&Vl[nd * 16 + lrow][((kc * 4 + kgrp) ^ (lrow & 7)) * 8];
        acc[nd] = MFMA(pa[kc], vb, acc[nd]);
      }
    __syncthreads();  // protect Vl / Kl[cur^1] before next iteration's STAGE
  }
#undef STAGE_K
#undef STAGE_V

#pragma unroll
  for (int nd = 0; nd < 8; ++nd)
#pragma unroll
    for (int r = 0; r < 4; ++r) {
      int row = qb * 128 + w * 16 + kgrp * 4 + r;
      O[((size_t)b * SS + row) * 2048 + h * HD + nd * 16 + lrow] =
          __float2bfloat16(acc[nd][r] / l_[r]);
    }
}

// ---------------- launch ----------------

extern "C" void kernel_launch(void* const* d_in, const int* in_sizes, int n_in,
                              void* d_out, int out_size, void* d_ws, size_t ws_size,
                              hipStream_t stream) {
  const float* hs = (const float*)d_in[0];
  const float* Wqkv = (const float*)d_in[1];
  const float* Wo = (const float*)d_in[2];
  const float* ctx_k = (const float*)d_in[3];
  const float* ctx_v = (const float*)d_in[4];
  const int* pid = (const int*)d_in[5];
  float* out = (float*)d_out;
  char* ws = (char*)d_ws;

  bf16* Hb = (bf16*)(ws);                      // 16.78 MB (reused as attn_out)
  bf16* WqT = (bf16*)(ws + 16777216);          // 16.78 MB
  bf16* WoT = (bf16*)(ws + 33554432);          // 8.39 MB
  bf16* qkv = (bf16*)(ws + 41943040);          // 33.55 MB
  bf16* Qb = (bf16*)(ws + 75497472);           // 16.78 MB
  bf16* Kfull = (bf16*)(ws + 92274688);        // 25.17 MB
  bf16* Vt = (bf16*)(ws + 117440512);          // 25.17 MB
  float* cosT = (float*)(ws + 142606336);      // 256 KB
  float* sinT = (float*)(ws + 142606336 + 262144);
  bf16* attn = Hb;  // alias: Hb dead after QKV GEMM

  rope_table<<<256, 256, 0, stream>>>(pid, cosT, sinT);
  cvt_bf16<<<4096, 256, 0, stream>>>(hs, Hb);
  transpose_cvt<<<dim3(128, 64), 256, 0, stream>>>(Wqkv, WqT, HID, QKVN);
  transpose_cvt<<<dim3(64, 64), 256, 0, stream>>>(Wo, WoT, 2048, 2048);
  ctxk_copy<<<4096, 256, 0, stream>>>(ctx_k, Kfull);
  ctxv_transpose<<<dim3(64, 4, 32), 256, 0, stream>>>(ctx_v, Vt);
  gemm_bt<bf16><<<dim3(QKVN / 128, MROWS / 128), 256, 0, stream>>>(
      Hb, WqT, qkv, MROWS, QKVN, HID);
  rope_q<<<16384, 256, 0, stream>>>(qkv, cosT, sinT, Qb);
  rope_k<<<8192, 256, 0, stream>>>(qkv, cosT, sinT, Kfull);
  vt_from_qkv<<<dim3(32, 4, 32), 256, 0, stream>>>(qkv, Vt);
  flash_attn<<<512, 512, 0, stream>>>(Qb, Kfull, Vt, attn);
  gemm_bt<float><<<dim3(2048 / 128, MROWS / 128), 256, 0, stream>>>(
      attn, WoT, out, MROWS, 2048, HID);
}

// Round 5
// 377.657 us; speedup vs baseline: 2.3210x; 1.0960x over previous
//
#include <hip/hip_runtime.h>
#include <hip/hip_bf16.h>
#include <stdint.h>

#define NH 16
#define NKV 8
#define HD 128
#define BB 4
#define SS 1024
#define CTXL 2048
#define LT 3072
#define HID 2048
#define QKVN 4096
#define MROWS 4096

typedef __hip_bfloat16 bf16;
using f32x4 = __attribute__((ext_vector_type(4))) float;
using s16x8 = __attribute__((ext_vector_type(8))) short;

#define MFMA(a, b, c) __builtin_amdgcn_mfma_f32_16x16x32_bf16((a), (b), (c), 0, 0, 0)

__device__ __forceinline__ void gload_lds16(const void* g, void* l) {
  __builtin_amdgcn_global_load_lds((const __attribute__((address_space(1))) void*)g,
                                   (__attribute__((address_space(3))) void*)l, 16, 0, 0);
}

__device__ __forceinline__ void store_bf8(bf16* dst, const float* f) {
  bf16 tmp[8];
#pragma unroll
  for (int j = 0; j < 8; ++j) tmp[j] = __float2bfloat16(f[j]);
  __builtin_memcpy((void*)dst, (const void*)tmp, 16);
}

// ---------------- prep kernels ----------------

__global__ void cvt_bf16(const float* __restrict__ in, bf16* __restrict__ out) {
  size_t tid = (size_t)blockIdx.x * 256 + threadIdx.x;  // one thread per 8 elems
  const float4* p = (const float4*)(in + tid * 8);
  float4 a = p[0], b = p[1];
  float f[8] = {a.x, a.y, a.z, a.w, b.x, b.y, b.z, b.w};
  store_bf8(out + tid * 8, f);
}

// out[c][r] = (bf16) in[r][c]
__global__ void transpose_cvt(const float* __restrict__ in, bf16* __restrict__ out,
                              int R, int C) {
  __shared__ float tile[32][33];
  int c0 = blockIdx.x * 32, r0 = blockIdx.y * 32;
  int tx = threadIdx.x & 31, ty = threadIdx.x >> 5;
#pragma unroll
  for (int i = 0; i < 32; i += 8)
    tile[ty + i][tx] = in[(size_t)(r0 + ty + i) * C + c0 + tx];
  __syncthreads();
#pragma unroll
  for (int i = 0; i < 32; i += 8)
    out[(size_t)(c0 + ty + i) * R + r0 + tx] = __float2bfloat16(tile[tx][ty + i]);
}

// ctx_k [b][l][h][d] f32 -> K_full [b][h][l][d] bf16 (l < CTXL)
__global__ void ctxk_copy(const float* __restrict__ ck, bf16* __restrict__ Kf) {
  int tid = blockIdx.x * 256 + threadIdx.x;
  int d8 = tid & 15, l = (tid >> 4) & 2047, h = (tid >> 15) & 7, b = tid >> 18;
  const float* s = ck + (((size_t)b * CTXL + l) * NKV + h) * HD + d8 * 8;
  const float4* p = (const float4*)s;
  float4 a = p[0], bb = p[1];
  float f[8] = {a.x, a.y, a.z, a.w, bb.x, bb.y, bb.z, bb.w};
  store_bf8(Kf + (((size_t)(b * NKV + h)) * LT + l) * HD + d8 * 8, f);
}

// ctx_v [b][l][h][d] f32 -> V_T [b][h][d][l] bf16 (l < CTXL)
__global__ void ctxv_transpose(const float* __restrict__ cv, bf16* __restrict__ Vt) {
  __shared__ float tile[32][33];
  int l0 = blockIdx.x * 32, d0 = blockIdx.y * 32;
  int b = blockIdx.z >> 3, h = blockIdx.z & 7;
  int tx = threadIdx.x & 31, ty = threadIdx.x >> 5;
#pragma unroll
  for (int i = 0; i < 32; i += 8)
    tile[ty + i][tx] = cv[(((size_t)b * CTXL + l0 + ty + i) * NKV + h) * HD + d0 + tx];
  __syncthreads();
#pragma unroll
  for (int i = 0; i < 32; i += 8)
    Vt[(((size_t)(b * NKV + h)) * HD + d0 + ty + i) * LT + l0 + tx] =
        __float2bfloat16(tile[tx][ty + i]);
}

// qkv v-slice -> V_T tail (l = CTXL + s)
__global__ void vt_from_qkv(const bf16* __restrict__ qkv, bf16* __restrict__ Vt) {
  __shared__ float tile[32][33];
  int s0 = blockIdx.x * 32, d0 = blockIdx.y * 32;
  int b = blockIdx.z >> 3, h = blockIdx.z & 7;
  int tx = threadIdx.x & 31, ty = threadIdx.x >> 5;
#pragma unroll
  for (int i = 0; i < 32; i += 8)
    tile[ty + i][tx] = __bfloat162float(
        qkv[((size_t)b * SS + s0 + ty + i) * QKVN + 3072 + h * HD + d0 + tx]);
  __syncthreads();
#pragma unroll
  for (int i = 0; i < 32; i += 8)
    Vt[(((size_t)(b * NKV + h)) * HD + d0 + ty + i) * LT + CTXL + s0 + tx] =
        __float2bfloat16(tile[tx][ty + i]);
}

__global__ void rope_table(const int* __restrict__ pid, float* __restrict__ cosT,
                           float* __restrict__ sinT) {
  int tid = blockIdx.x * 256 + threadIdx.x;  // S*64
  int j = tid & 63, s = tid >> 6;
  int sec = (j < 8) ? 0 : (j < 16) ? 1 : (j < 40) ? 2 : 3;
  float pos = (float)pid[sec * SS + s];
  float inv = __expf(-(float)j * 0.14391156831212787f);  // ln(10000)/64
  float a = pos * inv;
  cosT[tid] = cosf(a);
  sinT[tid] = sinf(a);
}

__global__ void rope_q(const bf16* __restrict__ qkv, const float* __restrict__ cosT,
                       const float* __restrict__ sinT, bf16* __restrict__ Q) {
  int tid = blockIdx.x * 256 + threadIdx.x;
  int j = tid & 63, h = (tid >> 6) & 15, s = (tid >> 10) & 1023, b = tid >> 20;
  const bf16* src = qkv + ((size_t)b * SS + s) * QKVN + h * HD;
  float x1 = __bfloat162float(src[j]), x2 = __bfloat162float(src[j + 64]);
  float c = cosT[s * 64 + j], sn = sinT[s * 64 + j];
  bf16* dst = Q + (((size_t)(b * NH + h)) * SS + s) * HD;
  dst[j] = __float2bfloat16(x1 * c - x2 * sn);
  dst[j + 64] = __float2bfloat16(x2 * c + x1 * sn);
}

__global__ void rope_k(const bf16* __restrict__ qkv, const float* __restrict__ cosT,
                       const float* __restrict__ sinT, bf16* __restrict__ Kf) {
  int tid = blockIdx.x * 256 + threadIdx.x;
  int j = tid & 63, h = (tid >> 6) & 7, s = (tid >> 9) & 1023, b = tid >> 19;
  const bf16* src = qkv + ((size_t)b * SS + s) * QKVN + 2048 + h * HD;
  float x1 = __bfloat162float(src[j]), x2 = __bfloat162float(src[j + 64]);
  float c = cosT[s * 64 + j], sn = sinT[s * 64 + j];
  bf16* dst = Kf + (((size_t)(b * NKV + h)) * LT + CTXL + s) * HD;
  dst[j] = __float2bfloat16(x1 * c - x2 * sn);
  dst[j + 64] = __float2bfloat16(x2 * c + x1 * sn);
}

// ---------------- GEMM: C[M][N] = A[M][K] * BT[N][K]^T ----------------

template <typename OT>
__global__ void gemm_bt(const bf16* __restrict__ A, const bf16* __restrict__ BT,
                        OT* __restrict__ C, int M, int N, int K) {
  __shared__ __attribute__((aligned(16))) short lA[128 * 64];
  __shared__ __attribute__((aligned(16))) short lB[128 * 64];
  const int t = threadIdx.x;
  const int lane = t & 63, w = t >> 6;
  const int wm = w >> 1, wn = w & 1;
  const int lrow = lane & 15, kgrp = lane >> 4;
  const int m0 = blockIdx.y * 128, n0 = blockIdx.x * 128;
  const int rowA = w * 32 + (lane >> 3);  // +c*8 per staging call
  const int kch = (lane & 7) * 8;
  const f32x4 fz = {0.f, 0.f, 0.f, 0.f};
  f32x4 acc[4][4];
#pragma unroll
  for (int i = 0; i < 4; ++i)
#pragma unroll
    for (int j = 0; j < 4; ++j) acc[i][j] = fz;

  for (int k0 = 0; k0 < K; k0 += 64) {
    const bf16* Ag = A + (size_t)(m0 + rowA) * K + k0 + kch;
    const bf16* Bg = BT + (size_t)(n0 + rowA) * K + k0 + kch;
#pragma unroll
    for (int c = 0; c < 4; ++c) {
      gload_lds16(Ag + (size_t)(c * 8) * K, &lA[(w * 32 + c * 8) * 64]);
      gload_lds16(Bg + (size_t)(c * 8) * K, &lB[(w * 32 + c * 8) * 64]);
    }
    __syncthreads();
#pragma unroll
    for (int kk = 0; kk < 64; kk += 32) {
      s16x8 af[4], bfr[4];
#pragma unroll
      for (int i = 0; i < 4; ++i)
        af[i] = *(const s16x8*)&lA[(wm * 64 + i * 16 + lrow) * 64 + kk + kgrp * 8];
#pragma unroll
      for (int j = 0; j < 4; ++j)
        bfr[j] = *(const s16x8*)&lB[(wn * 64 + j * 16 + lrow) * 64 + kk + kgrp * 8];
#pragma unroll
      for (int i = 0; i < 4; ++i)
#pragma unroll
        for (int j = 0; j < 4; ++j) acc[i][j] = MFMA(af[i], bfr[j], acc[i][j]);
    }
    __syncthreads();
  }
#pragma unroll
  for (int i = 0; i < 4; ++i)
#pragma unroll
    for (int j = 0; j < 4; ++j)
#pragma unroll
      for (int r = 0; r < 4; ++r) {
        int row = m0 + wm * 64 + i * 16 + kgrp * 4 + r;
        int col = n0 + wn * 64 + j * 16 + lrow;
        float v = acc[i][j][r];
        if constexpr (sizeof(OT) == 2)
          C[(size_t)row * N + col] = __float2bfloat16(v);
        else
          C[(size_t)row * N + col] = v;
      }
}

// ---------------- flash attention ----------------
// 256 q-rows/block, 8 waves x 32 rows (2 row-frags), KVBLK=64. K and V both
// double-buffered; ONE barrier per iteration (stage t+1 -> QK -> softmax ->
// PV -> barrier). Each kb/vb LDS fragment feeds 2 row-frags -> K/V LDS bytes
// per FLOP halved vs 16-rows/wave. exp2-domain softmax, deferred l-sum
// (per-lane partials, single end reduce), defer-max rescale skip (T13).
// XOR chunk swizzle on both sides (rule 21): K chunk^(row&15), V chunk^(row&7).

#define PSTR 72  // P row stride in elements: 144B = 16B-aligned
#define NT 48    // LT / 64
// scale * log2(e): softmax computed in exp2 domain
#define SCALE2 0.1275174335919605f

__global__ __launch_bounds__(512, 2) void flash_attn(
    const bf16* __restrict__ Q, const bf16* __restrict__ Kf,
    const bf16* __restrict__ Vt, bf16* __restrict__ O) {
  __shared__ __attribute__((aligned(16))) bf16 Kl[2][64][128];      // 32 KB
  __shared__ __attribute__((aligned(16))) bf16 Vl[2][128][64];      // 32 KB
  __shared__ __attribute__((aligned(16))) bf16 P_lds[8][32][PSTR];  // 36 KB
  const int t = threadIdx.x, lane = t & 63, w = t >> 6;
  const int qb = blockIdx.x & 3, h = (blockIdx.x >> 2) & 15, b = blockIdx.x >> 6;
  const int hk = h >> 1;
  const int lrow = lane & 15, kgrp = lane >> 4;
  const bf16* Kp = Kf + (size_t)(b * NKV + hk) * LT * HD;
  const bf16* Vp = Vt + (size_t)(b * NKV + hk) * HD * LT;

  const bf16* Qp = Q + (((size_t)(b * NH + h)) * SS + qb * 256 + w * 32) * HD;
  s16x8 qf[2][4];
#pragma unroll
  for (int f = 0; f < 2; ++f)
#pragma unroll
    for (int kd = 0; kd < 4; ++kd)
      qf[f][kd] = *(const s16x8*)&Qp[(f * 16 + lrow) * HD + kd * 32 + kgrp * 8];

  const f32x4 fz = {0.f, 0.f, 0.f, 0.f};
  f32x4 acc[2][8];
#pragma unroll
  for (int f = 0; f < 2; ++f)
#pragma unroll
    for (int i = 0; i < 8; ++i) acc[f][i] = fz;
  float m_[2][4], l_[2][4];
#pragma unroll
  for (int f = 0; f < 2; ++f)
#pragma unroll
    for (int r = 0; r < 4; ++r) { m_[f][r] = -1e30f; l_[f][r] = 0.f; }

  // staging geometry (8 waves, 512 threads)
#define STAGE_K(buf, l0)                                                        \
  do {                                                                          \
    _Pragma("unroll") for (int c = 0; c < 2; ++c) {                             \
      int row = w * 8 + c * 4 + (lane >> 4);                                    \
      gload_lds16(Kp + (size_t)((l0) + row) * HD + ((lane & 15) ^ (row & 15)) * 8, \
                  &Kl[buf][w * 8 + c * 4][0]);                                  \
    }                                                                           \
  } while (0)
#define STAGE_V(buf, l0)                                                        \
  do {                                                                          \
    _Pragma("unroll") for (int c = 0; c < 2; ++c) {                             \
      int d = w * 16 + c * 8 + (lane >> 3);                                     \
      gload_lds16(Vp + (size_t)d * LT + (l0) + ((lane & 7) ^ (d & 7)) * 8,      \
                  &Vl[buf][w * 16 + c * 8][0]);                                 \
    }                                                                           \
  } while (0)

  STAGE_K(0, 0);
  STAGE_V(0, 0);
  __syncthreads();

  for (int tt = 0; tt < NT; ++tt) {
    const int cur = tt & 1;
    if (tt + 1 < NT) {
      STAGE_K(cur ^ 1, (tt + 1) * 64);
      STAGE_V(cur ^ 1, (tt + 1) * 64);
    }

    // QK^T: each kb fragment feeds both row-frags
    f32x4 sc[2][4];
#pragma unroll
    for (int f = 0; f < 2; ++f)
#pragma unroll
      for (int cf = 0; cf < 4; ++cf) sc[f][cf] = fz;
#pragma unroll
    for (int cf = 0; cf < 4; ++cf)
#pragma unroll
      for (int kd = 0; kd < 4; ++kd) {
        s16x8 kb =
            *(const s16x8*)&Kl[cur][cf * 16 + lrow][((kd * 4 + kgrp) ^ lrow) * 8];
#pragma unroll
        for (int f = 0; f < 2; ++f) sc[f][cf] = MFMA(qf[f][kd], kb, sc[f][cf]);
      }

    // softmax (exp2 domain)
    float mx[2][4];
#pragma unroll
    for (int f = 0; f < 2; ++f)
#pragma unroll
      for (int r = 0; r < 4; ++r) {
        float a0 = fmaxf(sc[f][0][r], sc[f][1][r]);
        float a1 = fmaxf(sc[f][2][r], sc[f][3][r]);
        float m2 = fmaxf(a0, a1) * SCALE2;
#pragma unroll
        for (int off = 1; off < 16; off <<= 1)
          m2 = fmaxf(m2, __shfl_xor(m2, off, 16));
        mx[f][r] = m2;
      }
    bool nb = false;
#pragma unroll
    for (int f = 0; f < 2; ++f)
#pragma unroll
      for (int r = 0; r < 4; ++r) nb |= (mx[f][r] > m_[f][r] + 8.f);
    if (__any(nb)) {
      float so[2][4];
#pragma unroll
      for (int f = 0; f < 2; ++f)
#pragma unroll
        for (int r = 0; r < 4; ++r) {
          float mn = fmaxf(m_[f][r], mx[f][r]);
          so[f][r] = exp2f(m_[f][r] - mn);
          m_[f][r] = mn;
          l_[f][r] *= so[f][r];
        }
#pragma unroll
      for (int f = 0; f < 2; ++f)
#pragma unroll
        for (int nd = 0; nd < 8; ++nd)
#pragma unroll
          for (int r = 0; r < 4; ++r) acc[f][nd][r] *= so[f][r];
    }
    float rs[2][4] = {{0.f, 0.f, 0.f, 0.f}, {0.f, 0.f, 0.f, 0.f}};
#pragma unroll
    for (int f = 0; f < 2; ++f)
#pragma unroll
      for (int cf = 0; cf < 4; ++cf)
#pragma unroll
        for (int r = 0; r < 4; ++r) {
          float p = exp2f(sc[f][cf][r] * SCALE2 - m_[f][r]);
          rs[f][r] += p;
          P_lds[w][f * 16 + kgrp * 4 + r][cf * 16 + lrow] = __float2bfloat16(p);
        }
#pragma unroll
    for (int f = 0; f < 2; ++f)
#pragma unroll
      for (int r = 0; r < 4; ++r) l_[f][r] += rs[f][r];

    // per-wave LDS: in-wave write->read ordering via lgkmcnt, no barrier
    s16x8 pa[2][2];
#pragma unroll
    for (int f = 0; f < 2; ++f)
#pragma unroll
      for (int kc = 0; kc < 2; ++kc)
        pa[f][kc] = *(const s16x8*)&P_lds[w][f * 16 + lrow][kc * 32 + kgrp * 8];

    // PV: Vl[cur] was staged last iteration (drained at previous barrier);
    // each vb fragment feeds both row-frags
#pragma unroll
    for (int nd = 0; nd < 8; ++nd)
#pragma unroll
      for (int kc = 0; kc < 2; ++kc) {
        s16x8 vb = *(const s16x8*)&Vl[cur][nd * 16 + lrow]
                                     [((kc * 4 + kgrp) ^ (lrow & 7)) * 8];
#pragma unroll
        for (int f = 0; f < 2; ++f) acc[f][nd] = MFMA(pa[f][kc], vb, acc[f][nd]);
      }
    __syncthreads();  // drains stage(tt+1) DMA; protects bufs for next iter
  }
#undef STAGE_K
#undef STAGE_V

  // final l reduce across the 16-lane row group, then normalize + store
  float li[2][4];
#pragma unroll
  for (int f = 0; f < 2; ++f)
#pragma unroll
    for (int r = 0; r < 4; ++r) {
      float lv = l_[f][r];
#pragma unroll
      for (int off = 1; off < 16; off <<= 1) lv += __shfl_xor(lv, off, 16);
      li[f][r] = 1.f / lv;
    }
#pragma unroll
  for (int f = 0; f < 2; ++f)
#pragma unroll
    for (int nd = 0; nd < 8; ++nd)
#pragma unroll
      for (int r = 0; r < 4; ++r) {
        int row = qb * 256 + w * 32 + f * 16 + kgrp * 4 + r;
        O[((size_t)b * SS + row) * 2048 + h * HD + nd * 16 + lrow] =
            __float2bfloat16(acc[f][nd][r] * li[f][r]);
      }
}

// ---------------- launch ----------------

extern "C" void kernel_launch(void* const* d_in, const int* in_sizes, int n_in,
                              void* d_out, int out_size, void* d_ws, size_t ws_size,
                              hipStream_t stream) {
  const float* hs = (const float*)d_in[0];
  const float* Wqkv = (const float*)d_in[1];
  const float* Wo = (const float*)d_in[2];
  const float* ctx_k = (const float*)d_in[3];
  const float* ctx_v = (const float*)d_in[4];
  const int* pid = (const int*)d_in[5];
  float* out = (float*)d_out;
  char* ws = (char*)d_ws;

  bf16* Hb = (bf16*)(ws);                      // 16.78 MB (reused as attn_out)
  bf16* WqT = (bf16*)(ws + 16777216);          // 16.78 MB
  bf16* WoT = (bf16*)(ws + 33554432);          // 8.39 MB
  bf16* qkv = (bf16*)(ws + 41943040);          // 33.55 MB
  bf16* Qb = (bf16*)(ws + 75497472);           // 16.78 MB
  bf16* Kfull = (bf16*)(ws + 92274688);        // 25.17 MB
  bf16* Vt = (bf16*)(ws + 117440512);          // 25.17 MB
  float* cosT = (float*)(ws + 142606336);      // 256 KB
  float* sinT = (float*)(ws + 142606336 + 262144);
  bf16* attn = Hb;  // alias: Hb dead after QKV GEMM

  rope_table<<<256, 256, 0, stream>>>(pid, cosT, sinT);
  cvt_bf16<<<4096, 256, 0, stream>>>(hs, Hb);
  transpose_cvt<<<dim3(128, 64), 256, 0, stream>>>(Wqkv, WqT, HID, QKVN);
  transpose_cvt<<<dim3(64, 64), 256, 0, stream>>>(Wo, WoT, 2048, 2048);
  ctxk_copy<<<4096, 256, 0, stream>>>(ctx_k, Kfull);
  ctxv_transpose<<<dim3(64, 4, 32), 256, 0, stream>>>(ctx_v, Vt);
  gemm_bt<bf16><<<dim3(QKVN / 128, MROWS / 128), 256, 0, stream>>>(
      Hb, WqT, qkv, MROWS, QKVN, HID);
  rope_q<<<16384, 256, 0, stream>>>(qkv, cosT, sinT, Qb);
  rope_k<<<8192, 256, 0, stream>>>(qkv, cosT, sinT, Kfull);
  vt_from_qkv<<<dim3(32, 4, 32), 256, 0, stream>>>(qkv, Vt);
  flash_attn<<<256, 512, 0, stream>>>(Qb, Kfull, Vt, attn);
  gemm_bt<float><<<dim3(2048 / 128, MROWS / 128), 256, 0, stream>>>(
      attn, WoT, out, MROWS, 2048, HID);
}

// Round 6
// 354.175 us; speedup vs baseline: 2.4749x; 1.0663x over previous
//
#include <hip/hip_runtime.h>
#include <hip/hip_bf16.h>
#include <stdint.h>

#define NH 16
#define NKV 8
#define HD 128
#define BB 4
#define SS 1024
#define CTXL 2048
#define LT 3072
#define HID 2048
#define QKVN 4096
#define MROWS 4096

typedef __hip_bfloat16 bf16;
using f32x4 = __attribute__((ext_vector_type(4))) float;
using s16x8 = __attribute__((ext_vector_type(8))) short;

#define MFMA(a, b, c) __builtin_amdgcn_mfma_f32_16x16x32_bf16((a), (b), (c), 0, 0, 0)

__device__ __forceinline__ void gload_lds16(const void* g, void* l) {
  __builtin_amdgcn_global_load_lds((const __attribute__((address_space(1))) void*)g,
                                   (__attribute__((address_space(3))) void*)l, 16, 0, 0);
}

__device__ __forceinline__ void store_bf8(bf16* dst, const float* f) {
  bf16 tmp[8];
#pragma unroll
  for (int j = 0; j < 8; ++j) tmp[j] = __float2bfloat16(f[j]);
  __builtin_memcpy((void*)dst, (const void*)tmp, 16);
}

// ---------------- prep kernels ----------------

__global__ void cvt_bf16(const float* __restrict__ in, bf16* __restrict__ out) {
  size_t tid = (size_t)blockIdx.x * 256 + threadIdx.x;  // one thread per 8 elems
  const float4* p = (const float4*)(in + tid * 8);
  float4 a = p[0], b = p[1];
  float f[8] = {a.x, a.y, a.z, a.w, b.x, b.y, b.z, b.w};
  store_bf8(out + tid * 8, f);
}

// out[c][r] = (bf16) in[r][c]
__global__ void transpose_cvt(const float* __restrict__ in, bf16* __restrict__ out,
                              int R, int C) {
  __shared__ float tile[32][33];
  int c0 = blockIdx.x * 32, r0 = blockIdx.y * 32;
  int tx = threadIdx.x & 31, ty = threadIdx.x >> 5;
#pragma unroll
  for (int i = 0; i < 32; i += 8)
    tile[ty + i][tx] = in[(size_t)(r0 + ty + i) * C + c0 + tx];
  __syncthreads();
#pragma unroll
  for (int i = 0; i < 32; i += 8)
    out[(size_t)(c0 + ty + i) * R + r0 + tx] = __float2bfloat16(tile[tx][ty + i]);
}

// ctx_k [b][l][h][d] f32 -> K_full [b][h][l][d] bf16 (l < CTXL)
__global__ void ctxk_copy(const float* __restrict__ ck, bf16* __restrict__ Kf) {
  int tid = blockIdx.x * 256 + threadIdx.x;
  int d8 = tid & 15, l = (tid >> 4) & 2047, h = (tid >> 15) & 7, b = tid >> 18;
  const float* s = ck + (((size_t)b * CTXL + l) * NKV + h) * HD + d8 * 8;
  const float4* p = (const float4*)s;
  float4 a = p[0], bb = p[1];
  float f[8] = {a.x, a.y, a.z, a.w, bb.x, bb.y, bb.z, bb.w};
  store_bf8(Kf + (((size_t)(b * NKV + h)) * LT + l) * HD + d8 * 8, f);
}

// ctx_v [b][l][h][d] f32 -> V_T [b][h][d][l] bf16 (l < CTXL)
__global__ void ctxv_transpose(const float* __restrict__ cv, bf16* __restrict__ Vt) {
  __shared__ float tile[32][33];
  int l0 = blockIdx.x * 32, d0 = blockIdx.y * 32;
  int b = blockIdx.z >> 3, h = blockIdx.z & 7;
  int tx = threadIdx.x & 31, ty = threadIdx.x >> 5;
#pragma unroll
  for (int i = 0; i < 32; i += 8)
    tile[ty + i][tx] = cv[(((size_t)b * CTXL + l0 + ty + i) * NKV + h) * HD + d0 + tx];
  __syncthreads();
#pragma unroll
  for (int i = 0; i < 32; i += 8)
    Vt[(((size_t)(b * NKV + h)) * HD + d0 + ty + i) * LT + l0 + tx] =
        __float2bfloat16(tile[tx][ty + i]);
}

// qkv v-slice -> V_T tail (l = CTXL + s)
__global__ void vt_from_qkv(const bf16* __restrict__ qkv, bf16* __restrict__ Vt) {
  __shared__ float tile[32][33];
  int s0 = blockIdx.x * 32, d0 = blockIdx.y * 32;
  int b = blockIdx.z >> 3, h = blockIdx.z & 7;
  int tx = threadIdx.x & 31, ty = threadIdx.x >> 5;
#pragma unroll
  for (int i = 0; i < 32; i += 8)
    tile[ty + i][tx] = __bfloat162float(
        qkv[((size_t)b * SS + s0 + ty + i) * QKVN + 3072 + h * HD + d0 + tx]);
  __syncthreads();
#pragma unroll
  for (int i = 0; i < 32; i += 8)
    Vt[(((size_t)(b * NKV + h)) * HD + d0 + ty + i) * LT + CTXL + s0 + tx] =
        __float2bfloat16(tile[tx][ty + i]);
}

__global__ void rope_table(const int* __restrict__ pid, float* __restrict__ cosT,
                           float* __restrict__ sinT) {
  int tid = blockIdx.x * 256 + threadIdx.x;  // S*64
  int j = tid & 63, s = tid >> 6;
  int sec = (j < 8) ? 0 : (j < 16) ? 1 : (j < 40) ? 2 : 3;
  float pos = (float)pid[sec * SS + s];
  float inv = __expf(-(float)j * 0.14391156831212787f);  // ln(10000)/64
  float a = pos * inv;
  cosT[tid] = cosf(a);
  sinT[tid] = sinf(a);
}

__global__ void rope_q(const bf16* __restrict__ qkv, const float* __restrict__ cosT,
                       const float* __restrict__ sinT, bf16* __restrict__ Q) {
  int tid = blockIdx.x * 256 + threadIdx.x;
  int j = tid & 63, h = (tid >> 6) & 15, s = (tid >> 10) & 1023, b = tid >> 20;
  const bf16* src = qkv + ((size_t)b * SS + s) * QKVN + h * HD;
  float x1 = __bfloat162float(src[j]), x2 = __bfloat162float(src[j + 64]);
  float c = cosT[s * 64 + j], sn = sinT[s * 64 + j];
  bf16* dst = Q + (((size_t)(b * NH + h)) * SS + s) * HD;
  dst[j] = __float2bfloat16(x1 * c - x2 * sn);
  dst[j + 64] = __float2bfloat16(x2 * c + x1 * sn);
}

__global__ void rope_k(const bf16* __restrict__ qkv, const float* __restrict__ cosT,
                       const float* __restrict__ sinT, bf16* __restrict__ Kf) {
  int tid = blockIdx.x * 256 + threadIdx.x;
  int j = tid & 63, h = (tid >> 6) & 7, s = (tid >> 9) & 1023, b = tid >> 19;
  const bf16* src = qkv + ((size_t)b * SS + s) * QKVN + 2048 + h * HD;
  float x1 = __bfloat162float(src[j]), x2 = __bfloat162float(src[j + 64]);
  float c = cosT[s * 64 + j], sn = sinT[s * 64 + j];
  bf16* dst = Kf + (((size_t)(b * NKV + h)) * LT + CTXL + s) * HD;
  dst[j] = __float2bfloat16(x1 * c - x2 * sn);
  dst[j + 64] = __float2bfloat16(x2 * c + x1 * sn);
}

// ---------------- GEMM: C[M][N] = A[M][K] * BT[N][K]^T ----------------

template <typename OT>
__global__ void gemm_bt(const bf16* __restrict__ A, const bf16* __restrict__ BT,
                        OT* __restrict__ C, int M, int N, int K) {
  __shared__ __attribute__((aligned(16))) short lA[128 * 64];
  __shared__ __attribute__((aligned(16))) short lB[128 * 64];
  const int t = threadIdx.x;
  const int lane = t & 63, w = t >> 6;
  const int wm = w >> 1, wn = w & 1;
  const int lrow = lane & 15, kgrp = lane >> 4;
  const int m0 = blockIdx.y * 128, n0 = blockIdx.x * 128;
  const int rowA = w * 32 + (lane >> 3);  // +c*8 per staging call
  const int kch = (lane & 7) * 8;
  const f32x4 fz = {0.f, 0.f, 0.f, 0.f};
  f32x4 acc[4][4];
#pragma unroll
  for (int i = 0; i < 4; ++i)
#pragma unroll
    for (int j = 0; j < 4; ++j) acc[i][j] = fz;

  for (int k0 = 0; k0 < K; k0 += 64) {
    const bf16* Ag = A + (size_t)(m0 + rowA) * K + k0 + kch;
    const bf16* Bg = BT + (size_t)(n0 + rowA) * K + k0 + kch;
#pragma unroll
    for (int c = 0; c < 4; ++c) {
      gload_lds16(Ag + (size_t)(c * 8) * K, &lA[(w * 32 + c * 8) * 64]);
      gload_lds16(Bg + (size_t)(c * 8) * K, &lB[(w * 32 + c * 8) * 64]);
    }
    __syncthreads();
#pragma unroll
    for (int kk = 0; kk < 64; kk += 32) {
      s16x8 af[4], bfr[4];
#pragma unroll
      for (int i = 0; i < 4; ++i)
        af[i] = *(const s16x8*)&lA[(wm * 64 + i * 16 + lrow) * 64 + kk + kgrp * 8];
#pragma unroll
      for (int j = 0; j < 4; ++j)
        bfr[j] = *(const s16x8*)&lB[(wn * 64 + j * 16 + lrow) * 64 + kk + kgrp * 8];
#pragma unroll
      for (int i = 0; i < 4; ++i)
#pragma unroll
        for (int j = 0; j < 4; ++j) acc[i][j] = MFMA(af[i], bfr[j], acc[i][j]);
    }
    __syncthreads();
  }
#pragma unroll
  for (int i = 0; i < 4; ++i)
#pragma unroll
    for (int j = 0; j < 4; ++j)
#pragma unroll
      for (int r = 0; r < 4; ++r) {
        int row = m0 + wm * 64 + i * 16 + kgrp * 4 + r;
        int col = n0 + wn * 64 + j * 16 + lrow;
        float v = acc[i][j][r];
        if constexpr (sizeof(OT) == 2)
          C[(size_t)row * N + col] = __float2bfloat16(v);
        else
          C[(size_t)row * N + col] = v;
      }
}

// ---------------- flash attention ----------------
// 256 q-rows/block, 8 waves x 32 rows (2 row-frags), KVBLK=64, K/V double-
// buffered, ONE barrier per iteration. SWAPPED QK^T: sc = MFMA(K, Q) (A/B
// fragment lane-maps are identical, so the same loaded fragments work) ->
// lane holds 16 scores of ONE q-row (col=lane&15). Softmax is lane-local:
// 15 fmax + 2 wide shfls for max, l-sum is a per-(lane,kgrp) partial reduced
// once at the end, P packed as ds_write_b64. Defer-max (T13) rescale skip.
// XOR chunk swizzle on both sides (rule 21): K chunk^(row&15), V chunk^(row&7).

#define PSTR 72  // P row stride in elements: 144B = 16B-aligned
#define NT 48    // LT / 64
// scale * log2(e): softmax computed in exp2 domain
#define SCALE2 0.1275174335919605f

__global__ __launch_bounds__(512, 2) void flash_attn(
    const bf16* __restrict__ Q, const bf16* __restrict__ Kf,
    const bf16* __restrict__ Vt, bf16* __restrict__ O) {
  __shared__ __attribute__((aligned(16))) bf16 Kl[2][64][128];      // 32 KB
  __shared__ __attribute__((aligned(16))) bf16 Vl[2][128][64];      // 32 KB
  __shared__ __attribute__((aligned(16))) bf16 P_lds[8][32][PSTR];  // 36 KB
  const int t = threadIdx.x, lane = t & 63, w = t >> 6;
  const int qb = blockIdx.x & 3, h = (blockIdx.x >> 2) & 15, b = blockIdx.x >> 6;
  const int hk = h >> 1;
  const int lrow = lane & 15, kgrp = lane >> 4;
  const bf16* Kp = Kf + (size_t)(b * NKV + hk) * LT * HD;
  const bf16* Vp = Vt + (size_t)(b * NKV + hk) * HD * LT;

  const bf16* Qp = Q + (((size_t)(b * NH + h)) * SS + qb * 256 + w * 32) * HD;
  s16x8 qf[2][4];
#pragma unroll
  for (int f = 0; f < 2; ++f)
#pragma unroll
    for (int kd = 0; kd < 4; ++kd)
      qf[f][kd] = *(const s16x8*)&Qp[(f * 16 + lrow) * HD + kd * 32 + kgrp * 8];

  const f32x4 fz = {0.f, 0.f, 0.f, 0.f};
  f32x4 acc[2][8];
#pragma unroll
  for (int f = 0; f < 2; ++f)
#pragma unroll
    for (int i = 0; i < 8; ++i) acc[f][i] = fz;
  // per-lane: m_/l_ track q-row (lane&15) of each frag; l_ is the partial
  // sum over this lane's kv subset (cross-kgrp reduce deferred to epilogue)
  float m_[2] = {-1e30f, -1e30f}, l_[2] = {0.f, 0.f};

  // staging geometry (8 waves, 512 threads)
#define STAGE_K(buf, l0)                                                        \
  do {                                                                          \
    _Pragma("unroll") for (int c = 0; c < 2; ++c) {                             \
      int row = w * 8 + c * 4 + (lane >> 4);                                    \
      gload_lds16(Kp + (size_t)((l0) + row) * HD + ((lane & 15) ^ (row & 15)) * 8, \
                  &Kl[buf][w * 8 + c * 4][0]);                                  \
    }                                                                           \
  } while (0)
#define STAGE_V(buf, l0)                                                        \
  do {                                                                          \
    _Pragma("unroll") for (int c = 0; c < 2; ++c) {                             \
      int d = w * 16 + c * 8 + (lane >> 3);                                     \
      gload_lds16(Vp + (size_t)d * LT + (l0) + ((lane & 7) ^ (d & 7)) * 8,      \
                  &Vl[buf][w * 16 + c * 8][0]);                                 \
    }                                                                           \
  } while (0)

  STAGE_K(0, 0);
  STAGE_V(0, 0);
  __syncthreads();

  for (int tt = 0; tt < NT; ++tt) {
    const int cur = tt & 1;
    if (tt + 1 < NT) {
      STAGE_K(cur ^ 1, (tt + 1) * 64);
      STAGE_V(cur ^ 1, (tt + 1) * 64);
    }

    // QK^T swapped: sc[f][cf][r] = score for q-row (lane&15) of frag f,
    // kv = cf*16 + kgrp*4 + r
    f32x4 sc[2][4];
#pragma unroll
    for (int f = 0; f < 2; ++f)
#pragma unroll
      for (int cf = 0; cf < 4; ++cf) sc[f][cf] = fz;
#pragma unroll
    for (int cf = 0; cf < 4; ++cf)
#pragma unroll
      for (int kd = 0; kd < 4; ++kd) {
        s16x8 kb =
            *(const s16x8*)&Kl[cur][cf * 16 + lrow][((kd * 4 + kgrp) ^ lrow) * 8];
#pragma unroll
        for (int f = 0; f < 2; ++f) sc[f][cf] = MFMA(kb, qf[f][kd], sc[f][cf]);
      }

    // lane-local max over this lane's 16 scores, then 2 wide shfls
    float mxv[2];
#pragma unroll
    for (int f = 0; f < 2; ++f) {
      float a0 = fmaxf(fmaxf(sc[f][0][0], sc[f][0][1]),
                       fmaxf(sc[f][0][2], sc[f][0][3]));
      float a1 = fmaxf(fmaxf(sc[f][1][0], sc[f][1][1]),
                       fmaxf(sc[f][1][2], sc[f][1][3]));
      float a2 = fmaxf(fmaxf(sc[f][2][0], sc[f][2][1]),
                       fmaxf(sc[f][2][2], sc[f][2][3]));
      float a3 = fmaxf(fmaxf(sc[f][3][0], sc[f][3][1]),
                       fmaxf(sc[f][3][2], sc[f][3][3]));
      float mx = fmaxf(fmaxf(a0, a1), fmaxf(a2, a3)) * SCALE2;
      mx = fmaxf(mx, __shfl_xor(mx, 16, 64));
      mx = fmaxf(mx, __shfl_xor(mx, 32, 64));
      mxv[f] = mx;
    }
    bool nb = (mxv[0] > m_[0] + 8.f) || (mxv[1] > m_[1] + 8.f);
    if (__any(nb)) {
#pragma unroll
      for (int f = 0; f < 2; ++f) {
        float mn = fmaxf(m_[f], mxv[f]);
        float so = exp2f(m_[f] - mn);
        m_[f] = mn;
        l_[f] *= so;
        float sob[4];
#pragma unroll
        for (int r = 0; r < 4; ++r) sob[r] = __shfl(so, kgrp * 4 + r, 16);
#pragma unroll
        for (int nd = 0; nd < 8; ++nd)
#pragma unroll
          for (int r = 0; r < 4; ++r) acc[f][nd][r] *= sob[r];
      }
    }
    // P: exp2, accumulate lane-partial l, pack 4 bf16 -> one b64 store per cf
#pragma unroll
    for (int f = 0; f < 2; ++f) {
      float lp = 0.f;
#pragma unroll
      for (int cf = 0; cf < 4; ++cf) {
        bf16 pk[4];
#pragma unroll
        for (int r = 0; r < 4; ++r) {
          float p = exp2f(sc[f][cf][r] * SCALE2 - m_[f]);
          lp += p;
          pk[r] = __float2bfloat16(p);
        }
        __builtin_memcpy((void*)&P_lds[w][f * 16 + lrow][cf * 16 + kgrp * 4], pk, 8);
      }
      l_[f] += lp;
    }

    // per-wave LDS: in-wave write->read ordering via lgkmcnt, no barrier
    s16x8 pa[2][2];
#pragma unroll
    for (int f = 0; f < 2; ++f)
#pragma unroll
      for (int kc = 0; kc < 2; ++kc)
        pa[f][kc] = *(const s16x8*)&P_lds[w][f * 16 + lrow][kc * 32 + kgrp * 8];

    // PV: each vb fragment feeds both row-frags
#pragma unroll
    for (int nd = 0; nd < 8; ++nd)
#pragma unroll
      for (int kc = 0; kc < 2; ++kc) {
        s16x8 vb = *(const s16x8*)&Vl[cur][nd * 16 + lrow]
                                     [((kc * 4 + kgrp) ^ (lrow & 7)) * 8];
#pragma unroll
        for (int f = 0; f < 2; ++f) acc[f][nd] = MFMA(pa[f][kc], vb, acc[f][nd]);
      }
    __syncthreads();  // drains stage(tt+1) DMA; protects bufs for next iter
  }
#undef STAGE_K
#undef STAGE_V

  // epilogue: reduce l across kgrp (2 shfls), broadcast per acc-row, store
  float li[2][4];
#pragma unroll
  for (int f = 0; f < 2; ++f) {
    float lv = l_[f];
    lv += __shfl_xor(lv, 16, 64);
    lv += __shfl_xor(lv, 32, 64);
#pragma unroll
    for (int r = 0; r < 4; ++r) li[f][r] = 1.f / __shfl(lv, kgrp * 4 + r, 16);
  }
#pragma unroll
  for (int f = 0; f < 2; ++f)
#pragma unroll
    for (int nd = 0; nd < 8; ++nd)
#pragma unroll
      for (int r = 0; r < 4; ++r) {
        int row = qb * 256 + w * 32 + f * 16 + kgrp * 4 + r;
        O[((size_t)b * SS + row) * 2048 + h * HD + nd * 16 + lrow] =
            __float2bfloat16(acc[f][nd][r] * li[f][r]);
      }
}

// ---------------- launch ----------------

extern "C" void kernel_launch(void* const* d_in, const int* in_sizes, int n_in,
                              void* d_out, int out_size, void* d_ws, size_t ws_size,
                              hipStream_t stream) {
  const float* hs = (const float*)d_in[0];
  const float* Wqkv = (const float*)d_in[1];
  const float* Wo = (const float*)d_in[2];
  const float* ctx_k = (const float*)d_in[3];
  const float* ctx_v = (const float*)d_in[4];
  const int* pid = (const int*)d_in[5];
  float* out = (float*)d_out;
  char* ws = (char*)d_ws;

  bf16* Hb = (bf16*)(ws);                      // 16.78 MB (reused as attn_out)
  bf16* WqT = (bf16*)(ws + 16777216);          // 16.78 MB
  bf16* WoT = (bf16*)(ws + 33554432);          // 8.39 MB
  bf16* qkv = (bf16*)(ws + 41943040);          // 33.55 MB
  bf16* Qb = (bf16*)(ws + 75497472);           // 16.78 MB
  bf16* Kfull = (bf16*)(ws + 92274688);        // 25.17 MB
  bf16* Vt = (bf16*)(ws + 117440512);          // 25.17 MB
  float* cosT = (float*)(ws + 142606336);      // 256 KB
  float* sinT = (float*)(ws + 142606336 + 262144);
  bf16* attn = Hb;  // alias: Hb dead after QKV GEMM

  rope_table<<<256, 256, 0, stream>>>(pid, cosT, sinT);
  cvt_bf16<<<4096, 256, 0, stream>>>(hs, Hb);
  transpose_cvt<<<dim3(128, 64), 256, 0, stream>>>(Wqkv, WqT, HID, QKVN);
  transpose_cvt<<<dim3(64, 64), 256, 0, stream>>>(Wo, WoT, 2048, 2048);
  ctxk_copy<<<4096, 256, 0, stream>>>(ctx_k, Kfull);
  ctxv_transpose<<<dim3(64, 4, 32), 256, 0, stream>>>(ctx_v, Vt);
  gemm_bt<bf16><<<dim3(QKVN / 128, MROWS / 128), 256, 0, stream>>>(
      Hb, WqT, qkv, MROWS, QKVN, HID);
  rope_q<<<16384, 256, 0, stream>>>(qkv, cosT, sinT, Qb);
  rope_k<<<8192, 256, 0, stream>>>(qkv, cosT, sinT, Kfull);
  vt_from_qkv<<<dim3(32, 4, 32), 256, 0, stream>>>(qkv, Vt);
  flash_attn<<<256, 512, 0, stream>>>(Qb, Kfull, Vt, attn);
  gemm_bt<float><<<dim3(2048 / 128, MROWS / 128), 256, 0, stream>>>(
      attn, WoT, out, MROWS, 2048, HID);
}

// Round 7
// 351.430 us; speedup vs baseline: 2.4942x; 1.0078x over previous
//
#include <hip/hip_runtime.h>
#include <hip/hip_bf16.h>
#include <stdint.h>

#define NH 16
#define NKV 8
#define HD 128
#define BB 4
#define SS 1024
#define CTXL 2048
#define LT 3072
#define HID 2048
#define QKVN 4096
#define MROWS 4096

typedef __hip_bfloat16 bf16;
using f32x4 = __attribute__((ext_vector_type(4))) float;
using s16x8 = __attribute__((ext_vector_type(8))) short;

#define MFMA(a, b, c) __builtin_amdgcn_mfma_f32_16x16x32_bf16((a), (b), (c), 0, 0, 0)

__device__ __forceinline__ void gload_lds16(const void* g, void* l) {
  __builtin_amdgcn_global_load_lds((const __attribute__((address_space(1))) void*)g,
                                   (__attribute__((address_space(3))) void*)l, 16, 0, 0);
}

__device__ __forceinline__ void store_bf8(bf16* dst, const float* f) {
  bf16 tmp[8];
#pragma unroll
  for (int j = 0; j < 8; ++j) tmp[j] = __float2bfloat16(f[j]);
  __builtin_memcpy((void*)dst, (const void*)tmp, 16);
}

// ---------------- prep kernels ----------------

__global__ void cvt_bf16(const float* __restrict__ in, bf16* __restrict__ out) {
  size_t tid = (size_t)blockIdx.x * 256 + threadIdx.x;  // one thread per 8 elems
  const float4* p = (const float4*)(in + tid * 8);
  float4 a = p[0], b = p[1];
  float f[8] = {a.x, a.y, a.z, a.w, b.x, b.y, b.z, b.w};
  store_bf8(out + tid * 8, f);
}

// out[c][r] = (bf16) in[r][c]
__global__ void transpose_cvt(const float* __restrict__ in, bf16* __restrict__ out,
                              int R, int C) {
  __shared__ float tile[32][33];
  int c0 = blockIdx.x * 32, r0 = blockIdx.y * 32;
  int tx = threadIdx.x & 31, ty = threadIdx.x >> 5;
#pragma unroll
  for (int i = 0; i < 32; i += 8)
    tile[ty + i][tx] = in[(size_t)(r0 + ty + i) * C + c0 + tx];
  __syncthreads();
#pragma unroll
  for (int i = 0; i < 32; i += 8)
    out[(size_t)(c0 + ty + i) * R + r0 + tx] = __float2bfloat16(tile[tx][ty + i]);
}

// ctx_k [b][l][h][d] f32 -> K_full [b][h][l][d] bf16 (l < CTXL)
__global__ void ctxk_copy(const float* __restrict__ ck, bf16* __restrict__ Kf) {
  int tid = blockIdx.x * 256 + threadIdx.x;
  int d8 = tid & 15, l = (tid >> 4) & 2047, h = (tid >> 15) & 7, b = tid >> 18;
  const float* s = ck + (((size_t)b * CTXL + l) * NKV + h) * HD + d8 * 8;
  const float4* p = (const float4*)s;
  float4 a = p[0], bb = p[1];
  float f[8] = {a.x, a.y, a.z, a.w, bb.x, bb.y, bb.z, bb.w};
  store_bf8(Kf + (((size_t)(b * NKV + h)) * LT + l) * HD + d8 * 8, f);
}

// ctx_v [b][l][h][d] f32 -> V_T [b][h][d][l] bf16 (l < CTXL)
__global__ void ctxv_transpose(const float* __restrict__ cv, bf16* __restrict__ Vt) {
  __shared__ float tile[32][33];
  int l0 = blockIdx.x * 32, d0 = blockIdx.y * 32;
  int b = blockIdx.z >> 3, h = blockIdx.z & 7;
  int tx = threadIdx.x & 31, ty = threadIdx.x >> 5;
#pragma unroll
  for (int i = 0; i < 32; i += 8)
    tile[ty + i][tx] = cv[(((size_t)b * CTXL + l0 + ty + i) * NKV + h) * HD + d0 + tx];
  __syncthreads();
#pragma unroll
  for (int i = 0; i < 32; i += 8)
    Vt[(((size_t)(b * NKV + h)) * HD + d0 + ty + i) * LT + l0 + tx] =
        __float2bfloat16(tile[tx][ty + i]);
}

// qkv v-slice -> V_T tail (l = CTXL + s)
__global__ void vt_from_qkv(const bf16* __restrict__ qkv, bf16* __restrict__ Vt) {
  __shared__ float tile[32][33];
  int s0 = blockIdx.x * 32, d0 = blockIdx.y * 32;
  int b = blockIdx.z >> 3, h = blockIdx.z & 7;
  int tx = threadIdx.x & 31, ty = threadIdx.x >> 5;
#pragma unroll
  for (int i = 0; i < 32; i += 8)
    tile[ty + i][tx] = __bfloat162float(
        qkv[((size_t)b * SS + s0 + ty + i) * QKVN + 3072 + h * HD + d0 + tx]);
  __syncthreads();
#pragma unroll
  for (int i = 0; i < 32; i += 8)
    Vt[(((size_t)(b * NKV + h)) * HD + d0 + ty + i) * LT + CTXL + s0 + tx] =
        __float2bfloat16(tile[tx][ty + i]);
}

__global__ void rope_table(const int* __restrict__ pid, float* __restrict__ cosT,
                           float* __restrict__ sinT) {
  int tid = blockIdx.x * 256 + threadIdx.x;  // S*64
  int j = tid & 63, s = tid >> 6;
  int sec = (j < 8) ? 0 : (j < 16) ? 1 : (j < 40) ? 2 : 3;
  float pos = (float)pid[sec * SS + s];
  float inv = __expf(-(float)j * 0.14391156831212787f);  // ln(10000)/64
  float a = pos * inv;
  cosT[tid] = cosf(a);
  sinT[tid] = sinf(a);
}

__global__ void rope_q(const bf16* __restrict__ qkv, const float* __restrict__ cosT,
                       const float* __restrict__ sinT, bf16* __restrict__ Q) {
  int tid = blockIdx.x * 256 + threadIdx.x;
  int j = tid & 63, h = (tid >> 6) & 15, s = (tid >> 10) & 1023, b = tid >> 20;
  const bf16* src = qkv + ((size_t)b * SS + s) * QKVN + h * HD;
  float x1 = __bfloat162float(src[j]), x2 = __bfloat162float(src[j + 64]);
  float c = cosT[s * 64 + j], sn = sinT[s * 64 + j];
  bf16* dst = Q + (((size_t)(b * NH + h)) * SS + s) * HD;
  dst[j] = __float2bfloat16(x1 * c - x2 * sn);
  dst[j + 64] = __float2bfloat16(x2 * c + x1 * sn);
}

__global__ void rope_k(const bf16* __restrict__ qkv, const float* __restrict__ cosT,
                       const float* __restrict__ sinT, bf16* __restrict__ Kf) {
  int tid = blockIdx.x * 256 + threadIdx.x;
  int j = tid & 63, h = (tid >> 6) & 7, s = (tid >> 9) & 1023, b = tid >> 19;
  const bf16* src = qkv + ((size_t)b * SS + s) * QKVN + 2048 + h * HD;
  float x1 = __bfloat162float(src[j]), x2 = __bfloat162float(src[j + 64]);
  float c = cosT[s * 64 + j], sn = sinT[s * 64 + j];
  bf16* dst = Kf + (((size_t)(b * NKV + h)) * LT + CTXL + s) * HD;
  dst[j] = __float2bfloat16(x1 * c - x2 * sn);
  dst[j + 64] = __float2bfloat16(x2 * c + x1 * sn);
}

// ---------------- GEMM: C[M][N] = A[M][K] * BT[N][K]^T ----------------
// 256x128 tile, BK=64, 8 waves (4M x 2N), 512 threads. 3-buffer LDS (144 KB),
// prefetch depth 2, ONE barrier per K-tile, counted s_waitcnt vmcnt(6) (never
// 0 in main loop) -> staged loads stay in flight across barriers (T3/T4).
// XOR chunk swizzle both sides (rule 21): stage source chunk = (lane&7)^srow,
// read col chunk ^ (lrow&7) -> conflict-free ds_read_b128.
// Safety: pre-barrier lgkmcnt(0) drains pending ds_reads (rule 18/21); stage
// of tile t+2 targets buf (t-1)%3 whose reads completed before this barrier.

template <typename OT>
__global__ __launch_bounds__(512, 1) void gemm_bt(const bf16* __restrict__ A,
                                                  const bf16* __restrict__ BT,
                                                  OT* __restrict__ C, int M, int N,
                                                  int K) {
  __shared__ __attribute__((aligned(16))) bf16 lA[3][256][64];  // 96 KB
  __shared__ __attribute__((aligned(16))) bf16 lB[3][128][64];  // 48 KB
  const int t = threadIdx.x;
  const int lane = t & 63, w = t >> 6;
  const int wr = w >> 1, wc = w & 1;
  const int lrow = lane & 15, kgrp = lane >> 4;
  const int rchk = lrow & 7;  // read-side swizzle bits (frag row & 7)
  const int m0 = blockIdx.y * 256, n0 = blockIdx.x * 128;
  const int srow = lane >> 3;              // 0..7: row within 8-row group
  const int schk = (lane & 7) ^ srow;      // pre-swizzled source chunk
  const f32x4 fz = {0.f, 0.f, 0.f, 0.f};
  f32x4 acc[4][4];
#pragma unroll
  for (int i = 0; i < 4; ++i)
#pragma unroll
    for (int j = 0; j < 4; ++j) acc[i][j] = fz;
  const int NTK = K >> 6;

#define GSTAGE(ib, kt)                                                      \
  do {                                                                      \
    _Pragma("unroll") for (int c = 0; c < 4; ++c) {                         \
      int ra = c * 64 + w * 8 + srow;                                       \
      gload_lds16(A + (size_t)(m0 + ra) * K + (kt)*64 + schk * 8,           \
                  &lA[ib][c * 64 + w * 8][0]);                              \
    }                                                                       \
    _Pragma("unroll") for (int c = 0; c < 2; ++c) {                         \
      int rb = c * 64 + w * 8 + srow;                                       \
      gload_lds16(BT + (size_t)(n0 + rb) * K + (kt)*64 + schk * 8,          \
                  &lB[ib][c * 64 + w * 8][0]);                              \
    }                                                                       \
  } while (0)

  GSTAGE(0, 0);
  GSTAGE(1, 1);
  int ib = 0;
  for (int kt = 0; kt < NTK; ++kt) {
    // tile kt complete after this wait (6 = tile kt+1's loads stay in flight)
    if (kt + 1 < NTK)
      asm volatile("s_waitcnt vmcnt(6) lgkmcnt(0)" ::: "memory");
    else
      asm volatile("s_waitcnt vmcnt(0) lgkmcnt(0)" ::: "memory");
    __builtin_amdgcn_s_barrier();
    __builtin_amdgcn_sched_barrier(0);
    if (kt + 2 < NTK) {
      int ib2 = ib + 2;
      if (ib2 >= 3) ib2 -= 3;
      GSTAGE(ib2, kt + 2);
    }
#pragma unroll
    for (int kk = 0; kk < 2; ++kk) {
      s16x8 af[4], bf[4];
#pragma unroll
      for (int i = 0; i < 4; ++i)
        af[i] = *(const s16x8*)&lA[ib][wr * 64 + i * 16 + lrow]
                                     [(((kk << 2) + kgrp) ^ rchk) * 8];
#pragma unroll
      for (int j = 0; j < 4; ++j)
        bf[j] = *(const s16x8*)&lB[ib][wc * 64 + j * 16 + lrow]
                                     [(((kk << 2) + kgrp) ^ rchk) * 8];
#pragma unroll
      for (int i = 0; i < 4; ++i)
#pragma unroll
        for (int j = 0; j < 4; ++j) acc[i][j] = MFMA(af[i], bf[j], acc[i][j]);
    }
    ++ib;
    if (ib >= 3) ib = 0;
  }
#undef GSTAGE

#pragma unroll
  for (int i = 0; i < 4; ++i)
#pragma unroll
    for (int j = 0; j < 4; ++j)
#pragma unroll
      for (int r = 0; r < 4; ++r) {
        int row = m0 + wr * 64 + i * 16 + kgrp * 4 + r;
        int col = n0 + wc * 64 + j * 16 + lrow;
        float v = acc[i][j][r];
        if constexpr (sizeof(OT) == 2)
          C[(size_t)row * N + col] = __float2bfloat16(v);
        else
          C[(size_t)row * N + col] = v;
      }
}

// ---------------- flash attention ----------------
// 256 q-rows/block, 8 waves x 32 rows (2 row-frags), KVBLK=64, K/V double-
// buffered, ONE barrier per iteration. SWAPPED QK^T: sc = MFMA(K, Q) ->
// lane holds 16 scores of ONE q-row (col=lane&15). Softmax lane-local.
// XOR chunk swizzle both sides (rule 21): K chunk^(row&15), V chunk^(row&7).

#define PSTR 72  // P row stride in elements: 144B = 16B-aligned
#define NT 48    // LT / 64
// scale * log2(e): softmax computed in exp2 domain
#define SCALE2 0.1275174335919605f

__global__ __launch_bounds__(512, 2) void flash_attn(
    const bf16* __restrict__ Q, const bf16* __restrict__ Kf,
    const bf16* __restrict__ Vt, bf16* __restrict__ O) {
  __shared__ __attribute__((aligned(16))) bf16 Kl[2][64][128];      // 32 KB
  __shared__ __attribute__((aligned(16))) bf16 Vl[2][128][64];      // 32 KB
  __shared__ __attribute__((aligned(16))) bf16 P_lds[8][32][PSTR];  // 36 KB
  const int t = threadIdx.x, lane = t & 63, w = t >> 6;
  const int qb = blockIdx.x & 3, h = (blockIdx.x >> 2) & 15, b = blockIdx.x >> 6;
  const int hk = h >> 1;
  const int lrow = lane & 15, kgrp = lane >> 4;
  const bf16* Kp = Kf + (size_t)(b * NKV + hk) * LT * HD;
  const bf16* Vp = Vt + (size_t)(b * NKV + hk) * HD * LT;

  const bf16* Qp = Q + (((size_t)(b * NH + h)) * SS + qb * 256 + w * 32) * HD;
  s16x8 qf[2][4];
#pragma unroll
  for (int f = 0; f < 2; ++f)
#pragma unroll
    for (int kd = 0; kd < 4; ++kd)
      qf[f][kd] = *(const s16x8*)&Qp[(f * 16 + lrow) * HD + kd * 32 + kgrp * 8];

  const f32x4 fz = {0.f, 0.f, 0.f, 0.f};
  f32x4 acc[2][8];
#pragma unroll
  for (int f = 0; f < 2; ++f)
#pragma unroll
    for (int i = 0; i < 8; ++i) acc[f][i] = fz;
  // per-lane: m_/l_ track q-row (lane&15) of each frag; l_ is the partial
  // sum over this lane's kv subset (cross-kgrp reduce deferred to epilogue)
  float m_[2] = {-1e30f, -1e30f}, l_[2] = {0.f, 0.f};

  // staging geometry (8 waves, 512 threads)
#define STAGE_K(buf, l0)                                                        \
  do {                                                                          \
    _Pragma("unroll") for (int c = 0; c < 2; ++c) {                             \
      int row = w * 8 + c * 4 + (lane >> 4);                                    \
      gload_lds16(Kp + (size_t)((l0) + row) * HD + ((lane & 15) ^ (row & 15)) * 8, \
                  &Kl[buf][w * 8 + c * 4][0]);                                  \
    }                                                                           \
  } while (0)
#define STAGE_V(buf, l0)                                                        \
  do {                                                                          \
    _Pragma("unroll") for (int c = 0; c < 2; ++c) {                             \
      int d = w * 16 + c * 8 + (lane >> 3);                                     \
      gload_lds16(Vp + (size_t)d * LT + (l0) + ((lane & 7) ^ (d & 7)) * 8,      \
                  &Vl[buf][w * 16 + c * 8][0]);                                 \
    }                                                                           \
  } while (0)

  STAGE_K(0, 0);
  STAGE_V(0, 0);
  __syncthreads();

  for (int tt = 0; tt < NT; ++tt) {
    const int cur = tt & 1;
    if (tt + 1 < NT) {
      STAGE_K(cur ^ 1, (tt + 1) * 64);
      STAGE_V(cur ^ 1, (tt + 1) * 64);
    }

    // QK^T swapped: sc[f][cf][r] = score for q-row (lane&15) of frag f,
    // kv = cf*16 + kgrp*4 + r
    f32x4 sc[2][4];
#pragma unroll
    for (int f = 0; f < 2; ++f)
#pragma unroll
      for (int cf = 0; cf < 4; ++cf) sc[f][cf] = fz;
#pragma unroll
    for (int cf = 0; cf < 4; ++cf)
#pragma unroll
      for (int kd = 0; kd < 4; ++kd) {
        s16x8 kb =
            *(const s16x8*)&Kl[cur][cf * 16 + lrow][((kd * 4 + kgrp) ^ lrow) * 8];
#pragma unroll
        for (int f = 0; f < 2; ++f) sc[f][cf] = MFMA(kb, qf[f][kd], sc[f][cf]);
      }

    // lane-local max over this lane's 16 scores, then 2 wide shfls
    float mxv[2];
#pragma unroll
    for (int f = 0; f < 2; ++f) {
      float a0 = fmaxf(fmaxf(sc[f][0][0], sc[f][0][1]),
                       fmaxf(sc[f][0][2], sc[f][0][3]));
      float a1 = fmaxf(fmaxf(sc[f][1][0], sc[f][1][1]),
                       fmaxf(sc[f][1][2], sc[f][1][3]));
      float a2 = fmaxf(fmaxf(sc[f][2][0], sc[f][2][1]),
                       fmaxf(sc[f][2][2], sc[f][2][3]));
      float a3 = fmaxf(fmaxf(sc[f][3][0], sc[f][3][1]),
                       fmaxf(sc[f][3][2], sc[f][3][3]));
      float mx = fmaxf(fmaxf(a0, a1), fmaxf(a2, a3)) * SCALE2;
      mx = fmaxf(mx, __shfl_xor(mx, 16, 64));
      mx = fmaxf(mx, __shfl_xor(mx, 32, 64));
      mxv[f] = mx;
    }
    bool nb = (mxv[0] > m_[0] + 8.f) || (mxv[1] > m_[1] + 8.f);
    if (__any(nb)) {
#pragma unroll
      for (int f = 0; f < 2; ++f) {
        float mn = fmaxf(m_[f], mxv[f]);
        float so = exp2f(m_[f] - mn);
        m_[f] = mn;
        l_[f] *= so;
        float sob[4];
#pragma unroll
        for (int r = 0; r < 4; ++r) sob[r] = __shfl(so, kgrp * 4 + r, 16);
#pragma unroll
        for (int nd = 0; nd < 8; ++nd)
#pragma unroll
          for (int r = 0; r < 4; ++r) acc[f][nd][r] *= sob[r];
      }
    }
    // P: exp2, accumulate lane-partial l, pack 4 bf16 -> one b64 store per cf
#pragma unroll
    for (int f = 0; f < 2; ++f) {
      float lp = 0.f;
#pragma unroll
      for (int cf = 0; cf < 4; ++cf) {
        bf16 pk[4];
#pragma unroll
        for (int r = 0; r < 4; ++r) {
          float p = exp2f(sc[f][cf][r] * SCALE2 - m_[f]);
          lp += p;
          pk[r] = __float2bfloat16(p);
        }
        __builtin_memcpy((void*)&P_lds[w][f * 16 + lrow][cf * 16 + kgrp * 4], pk, 8);
      }
      l_[f] += lp;
    }

    // per-wave LDS: in-wave write->read ordering via lgkmcnt, no barrier
    s16x8 pa[2][2];
#pragma unroll
    for (int f = 0; f < 2; ++f)
#pragma unroll
      for (int kc = 0; kc < 2; ++kc)
        pa[f][kc] = *(const s16x8*)&P_lds[w][f * 16 + lrow][kc * 32 + kgrp * 8];

    // PV: each vb fragment feeds both row-frags
#pragma unroll
    for (int nd = 0; nd < 8; ++nd)
#pragma unroll
      for (int kc = 0; kc < 2; ++kc) {
        s16x8 vb = *(const s16x8*)&Vl[cur][nd * 16 + lrow]
                                     [((kc * 4 + kgrp) ^ (lrow & 7)) * 8];
#pragma unroll
        for (int f = 0; f < 2; ++f) acc[f][nd] = MFMA(pa[f][kc], vb, acc[f][nd]);
      }
    __syncthreads();  // drains stage(tt+1) DMA; protects bufs for next iter
  }
#undef STAGE_K
#undef STAGE_V

  // epilogue: reduce l across kgrp (2 shfls), broadcast per acc-row, store
  float li[2][4];
#pragma unroll
  for (int f = 0; f < 2; ++f) {
    float lv = l_[f];
    lv += __shfl_xor(lv, 16, 64);
    lv += __shfl_xor(lv, 32, 64);
#pragma unroll
    for (int r = 0; r < 4; ++r) li[f][r] = 1.f / __shfl(lv, kgrp * 4 + r, 16);
  }
#pragma unroll
  for (int f = 0; f < 2; ++f)
#pragma unroll
    for (int nd = 0; nd < 8; ++nd)
#pragma unroll
      for (int r = 0; r < 4; ++r) {
        int row = qb * 256 + w * 32 + f * 16 + kgrp * 4 + r;
        O[((size_t)b * SS + row) * 2048 + h * HD + nd * 16 + lrow] =
            __float2bfloat16(acc[f][nd][r] * li[f][r]);
      }
}

// ---------------- launch ----------------

extern "C" void kernel_launch(void* const* d_in, const int* in_sizes, int n_in,
                              void* d_out, int out_size, void* d_ws, size_t ws_size,
                              hipStream_t stream) {
  const float* hs = (const float*)d_in[0];
  const float* Wqkv = (const float*)d_in[1];
  const float* Wo = (const float*)d_in[2];
  const float* ctx_k = (const float*)d_in[3];
  const float* ctx_v = (const float*)d_in[4];
  const int* pid = (const int*)d_in[5];
  float* out = (float*)d_out;
  char* ws = (char*)d_ws;

  bf16* Hb = (bf16*)(ws);                      // 16.78 MB (reused as attn_out)
  bf16* WqT = (bf16*)(ws + 16777216);          // 16.78 MB
  bf16* WoT = (bf16*)(ws + 33554432);          // 8.39 MB
  bf16* qkv = (bf16*)(ws + 41943040);          // 33.55 MB
  bf16* Qb = (bf16*)(ws + 75497472);           // 16.78 MB
  bf16* Kfull = (bf16*)(ws + 92274688);        // 25.17 MB
  bf16* Vt = (bf16*)(ws + 117440512);          // 25.17 MB
  float* cosT = (float*)(ws + 142606336);      // 256 KB
  float* sinT = (float*)(ws + 142606336 + 262144);
  bf16* attn = Hb;  // alias: Hb dead after QKV GEMM

  rope_table<<<256, 256, 0, stream>>>(pid, cosT, sinT);
  cvt_bf16<<<4096, 256, 0, stream>>>(hs, Hb);
  transpose_cvt<<<dim3(128, 64), 256, 0, stream>>>(Wqkv, WqT, HID, QKVN);
  transpose_cvt<<<dim3(64, 64), 256, 0, stream>>>(Wo, WoT, 2048, 2048);
  ctxk_copy<<<4096, 256, 0, stream>>>(ctx_k, Kfull);
  ctxv_transpose<<<dim3(64, 4, 32), 256, 0, stream>>>(ctx_v, Vt);
  gemm_bt<bf16><<<dim3(QKVN / 128, MROWS / 256), 512, 0, stream>>>(
      Hb, WqT, qkv, MROWS, QKVN, HID);
  rope_q<<<16384, 256, 0, stream>>>(qkv, cosT, sinT, Qb);
  rope_k<<<8192, 256, 0, stream>>>(qkv, cosT, sinT, Kfull);
  vt_from_qkv<<<dim3(32, 4, 32), 256, 0, stream>>>(qkv, Vt);
  flash_attn<<<256, 512, 0, stream>>>(Qb, Kfull, Vt, attn);
  gemm_bt<float><<<dim3(2048 / 128, MROWS / 256), 512, 0, stream>>>(
      attn, WoT, out, MROWS, 2048, HID);
}